// Round 15
// baseline (703.599 us; speedup 1.0000x reference)
//
#include <hip/hip_runtime.h>
#include <hip/hip_bf16.h>

#define NN 20000
#define EE 160000

typedef __attribute__((ext_vector_type(8))) short bf16x8;
typedef __attribute__((ext_vector_type(4))) float f32x4;

__device__ __forceinline__ unsigned short f2bf(float f) {
    unsigned int u = __float_as_uint(f);
    u += 0x7FFFu + ((u >> 16) & 1);   // RNE
    return (unsigned short)(u >> 16);
}
__device__ __forceinline__ float bf2f(short s) {
    return __uint_as_float(((unsigned int)(unsigned short)s) << 16);
}
__device__ __forceinline__ bf16x8 pack8(float4 a, float4 b) {
    bf16x8 r;
    r[0] = (short)f2bf(a.x); r[1] = (short)f2bf(a.y);
    r[2] = (short)f2bf(a.z); r[3] = (short)f2bf(a.w);
    r[4] = (short)f2bf(b.x); r[5] = (short)f2bf(b.y);
    r[6] = (short)f2bf(b.z); r[7] = (short)f2bf(b.w);
    return r;
}

#define SH_STRIDE 136
#define SW_STRIDE 56

// barrier that does NOT drain vmcnt (gathers stay in flight)
__device__ __forceinline__ void bar_lgkm() {
    asm volatile("s_waitcnt lgkmcnt(0)\n\ts_barrier" ::: "memory");
}

__device__ __forceinline__ void mfma_sweep_lds(f32x4 (&acc)[2][8], bf16x8 a0, bf16x8 a1,
                                               const short* sWb, int lm, int lq)
{
#pragma unroll
    for (int ct = 0; ct < 8; ++ct) {
        bf16x8 b = *(const bf16x8*)(sWb + (ct * 16 + lm) * SW_STRIDE + lq * 8);
        acc[0][ct] = __builtin_amdgcn_mfma_f32_16x16x32_bf16(a0, b, acc[0][ct], 0, 0, 0);
        acc[1][ct] = __builtin_amdgcn_mfma_f32_16x16x32_bf16(a1, b, acc[1][ct], 0, 0, 0);
    }
}

// W-chunk pipeline: load (registers, issued early) / store (ds_write, later).
template<int NT>
struct WStage { bf16x8 v[512 / NT]; };

template<int NT>
__device__ __forceinline__ void wload(WStage<NT>& ws, const short* __restrict__ Wt,
                                      int Kpad, int k0, int tid)
{
#pragma unroll
    for (int j = 0; j < 256 / NT; ++j) {
        int i = tid + j * NT;
        int r = i >> 1, h = i & 1;
        const short* src = Wt + (size_t)r * Kpad + k0 + h * 16;
        ws.v[2 * j]     = *(const bf16x8*)src;
        ws.v[2 * j + 1] = *(const bf16x8*)(src + 8);
    }
}
template<int NT>
__device__ __forceinline__ void wstore(const WStage<NT>& ws, short* __restrict__ sW, int tid)
{
#pragma unroll
    for (int j = 0; j < 256 / NT; ++j) {
        int i = tid + j * NT;
        int r = i >> 1, h = i & 1;
        short* dst = sW + r * SW_STRIDE + h * 16;
        *(bf16x8*)dst       = ws.v[2 * j];
        *(bf16x8*)(dst + 8) = ws.v[2 * j + 1];
    }
}

__device__ __forceinline__ void zero_acc(f32x4 (&acc)[2][8]) {
#pragma unroll
    for (int i = 0; i < 2; ++i)
#pragma unroll
        for (int j = 0; j < 8; ++j) acc[i][j] = (f32x4)(0.f);
}

__device__ __forceinline__ void park(const f32x4 (&acc)[2][8], const float* __restrict__ bias,
                                     short* __restrict__ sH, int w32, int lm, int lq)
{
#pragma unroll
    for (int ct = 0; ct < 8; ++ct) {
        float bb = bias[ct * 16 + lm];
#pragma unroll
        for (int rt = 0; rt < 2; ++rt) {
            int rbase = w32 + rt * 16 + lq * 4;
#pragma unroll
            for (int reg = 0; reg < 4; ++reg) {
                float v = fmaxf(acc[rt][ct][reg] + bb, 0.f);
                sH[(rbase + reg) * SH_STRIDE + ct * 16 + lm] = (short)f2bf(v);
            }
        }
    }
}

// generic W-pipelined 128x128 layer from sH -> acc
template<int NT>
__device__ __forceinline__ void layer128(f32x4 (&acc)[2][8], const short* __restrict__ Wt,
                                         const short* sH, short* sW, int w32, int lm, int lq,
                                         int tid)
{
    zero_acc(acc);
    WStage<NT> ws, wsn;
    wload<NT>(ws, Wt, 128, 0, tid);
#pragma unroll
    for (int c = 0; c < 4; ++c) {
        if (c + 1 < 4) wload<NT>(wsn, Wt, 128, (c + 1) * 32, tid);
        bf16x8 a0 = *(const bf16x8*)&sH[(w32 + lm) * SH_STRIDE + c * 32 + lq * 8];
        bf16x8 a1 = *(const bf16x8*)&sH[(w32 + 16 + lm) * SH_STRIDE + c * 32 + lq * 8];
        bar_lgkm();
        wstore<NT>(ws, sW, tid);
        bar_lgkm();
        mfma_sweep_lds(acc, a0, a1, sW, lm, lq);
        ws = wsn;
    }
}

struct Frag {
    bf16x8 a0, a1;
    float4 f0, f1, f2, f3;
    int isF;
};

template<int MODE>
__device__ __forceinline__ void load_frag(Frag& fr, int c,
    const short* __restrict__ nfb, const float* __restrict__ eff,
    const float* __restrict__ aggf,
    int iS0, int iS1, int iR0, int iR1, size_t eO0, size_t eO1,
    int r0m, int r1m, const short* sH, int w32, int lm, int lq)
{
    int kq = lq * 8;
    fr.isF = 0;
    if (MODE == 0) {
        fr.a0 = *(const bf16x8*)&sH[(w32 + lm) * SH_STRIDE + c * 32 + kq];
        fr.a1 = *(const bf16x8*)&sH[(w32 + 16 + lm) * SH_STRIDE + c * 32 + kq];
    } else if (MODE == 1) {
        int seg = c >> 2, kb = (c & 3) * 32 + kq;
        if (seg == 0) {
            fr.a0 = *(const bf16x8*)(nfb + (size_t)iS0 * 128 + kb);
            fr.a1 = *(const bf16x8*)(nfb + (size_t)iS1 * 128 + kb);
        } else if (seg == 1) {
            fr.a0 = *(const bf16x8*)(nfb + (size_t)iR0 * 128 + kb);
            fr.a1 = *(const bf16x8*)(nfb + (size_t)iR1 * 128 + kb);
        } else {
            const float* p0 = eff + eO0 + kb;      // slot-contiguous (ef stored sorted)
            const float* p1 = eff + eO1 + kb;
            fr.f0 = *(const float4*)p0; fr.f1 = *(const float4*)(p0 + 4);
            fr.f2 = *(const float4*)p1; fr.f3 = *(const float4*)(p1 + 4);
            fr.isF = 1;
        }
    } else {  // MODE 2/4: node concat(nf, agg)
        int seg = c >> 2, kb = (c & 3) * 32 + kq;
        if (seg == 0) {
            fr.a0 = *(const bf16x8*)(nfb + (size_t)r0m * 128 + kb);
            fr.a1 = *(const bf16x8*)(nfb + (size_t)r1m * 128 + kb);
        } else {
            const float* p0 = aggf + (size_t)r0m * 128 + kb;
            const float* p1 = aggf + (size_t)r1m * 128 + kb;
            fr.f0 = *(const float4*)p0; fr.f1 = *(const float4*)(p0 + 4);
            fr.f2 = *(const float4*)p1; fr.f3 = *(const float4*)(p1 + 4);
            fr.isF = 1;
        }
    }
}

// NW waves per block, 32 rows per wave. MODE: 0 encoder (eList = optional src
// gather map); 1 edge (sorted slots, ef slot-ordered; resid=0 skips dead ef
// writeback on the last step); 2 node (zeroes own agg rows); 4 node+decoder
// fused (last step: nf never materialized, decoder runs from LDS).
template<int NW, int MODE>
__global__ __launch_bounds__(NW * 64) void gnn_mlp(
    const short* __restrict__ Wt0,
    const short* __restrict__ Wt1, const short* __restrict__ Wt2,
    const short* __restrict__ Wt3, const short* __restrict__ Wt4,   // MODE4: dec W0, W1
    const float* __restrict__ b0, const float* __restrict__ b1, const float* __restrict__ b2,
    const float* __restrict__ db0, const float* __restrict__ db1, const float* __restrict__ db2,
    const float* __restrict__ g, const float* __restrict__ be,
    const float* __restrict__ A0f, int K0,          // mode0: src; mode4: dec_W2 [128x3]
    const short* __restrict__ nfb,
    const float* __restrict__ eff,
    const float* __restrict__ aggf,
    const int* __restrict__ eList,
    const int* __restrict__ senders, const int* __restrict__ receivers,
    float* __restrict__ outF, short* __restrict__ outB,
    float* __restrict__ aggOut,
    float* __restrict__ decOut,
    int M, int resid)
{
    constexpr int KP0 = (MODE == 1) ? 384 : (MODE == 2 || MODE == 4) ? 256 : 32;
    constexpr int nC0 = KP0 / 32;
    __shared__ short sH[NW * 32 * SH_STRIDE];
    __shared__ short sW[128 * SW_STRIDE];
    __shared__ int sRcv[NW * 32], sSnd[NW * 32];
    const int tid = threadIdx.x;
    const int lane = tid & 63;
    const int w = tid >> 6;
    const int lm = lane & 15;
    const int lq = lane >> 4;
    const int w32 = w * 32;
    const int m0 = blockIdx.x * (NW * 32);
    constexpr int NT = NW * 64;

    if (MODE == 1) {
        if (tid < NW * 32) {
            int slot = m0 + tid;                       // grid exact: slot < E
            int e = eList ? eList[slot] : slot;
            sRcv[tid] = receivers[e];
            sSnd[tid] = senders[e];
        }
        bar_lgkm();
    }

    f32x4 acc[2][8];
    zero_acc(acc);

    // -------- layer 0 (depth-2 gather pipeline, depth-1 W, lgkm barriers) ----
    if (MODE == 0) {
#pragma unroll
        for (int i = 0; i < 16; ++i) {
            int flat = lane + i * 64;
            int r = flat >> 5, k = flat & 31;
            int row = m0 + w32 + r;
            float v = 0.f;
            if (k < K0 && row < M) {
                int src = eList ? eList[row] : row;    // gather source rows (sorted write)
                v = A0f[(size_t)src * K0 + k];
            }
            sH[(w32 + r) * SH_STRIDE + k] = (short)f2bf(v);
        }
    }
    int iS0 = 0, iS1 = 0, iR0 = 0, iR1 = 0;
    size_t eO0 = 0, eO1 = 0;
    if (MODE == 1) {
        // rt-interleaved: MFMA row m of tile rt <-> sorted slot w32 + 2*m + rt.
        int s0 = w32 + 2 * lm, s1 = s0 + 1;
        iS0 = sSnd[s0]; iS1 = sSnd[s1];
        iR0 = sRcv[s0]; iR1 = sRcv[s1];
        eO0 = (size_t)(m0 + s0) * 128;                 // ef is slot-ordered: contiguous
        eO1 = (size_t)(m0 + s1) * 128;
    }
    const int r0m = min(m0 + w32 + lm, M - 1);
    const int r1m = min(m0 + w32 + 16 + lm, M - 1);

    {
        WStage<NT> ws, wsn;
        Frag cur, nx1, nx2;
        wload<NT>(ws, Wt0, KP0, 0, tid);               // W(0) before any gathers
        load_frag<MODE>(cur, 0, nfb, eff, aggf, iS0, iS1, iR0, iR1, eO0, eO1,
                        r0m, r1m, sH, w32, lm, lq);
        if (nC0 > 1)
            load_frag<MODE>(nx1, 1, nfb, eff, aggf, iS0, iS1, iR0, iR1, eO0, eO1,
                            r0m, r1m, sH, w32, lm, lq);
#pragma unroll
        for (int c = 0; c < nC0; ++c) {
            if (c + 1 < nC0)
                wload<NT>(wsn, Wt0, KP0, (c + 1) * 32, tid);
            if (c + 2 < nC0)
                load_frag<MODE>(nx2, c + 2, nfb, eff, aggf, iS0, iS1, iR0, iR1, eO0, eO1,
                                r0m, r1m, sH, w32, lm, lq);
            bar_lgkm();                 // waves done reading previous sW chunk
            wstore<NT>(ws, sW, tid);    // vmcnt targets W(c); frags c+1,c+2 + W(c+1) in flight
            bar_lgkm();                 // chunk staged
            bf16x8 u0, u1;
            if (cur.isF) { u0 = pack8(cur.f0, cur.f1); u1 = pack8(cur.f2, cur.f3); }
            else         { u0 = cur.a0;               u1 = cur.a1; }
            mfma_sweep_lds(acc, u0, u1, sW, lm, lq);
            ws = wsn; cur = nx1; nx1 = nx2;
        }
    }
    bar_lgkm();
    park(acc, b0, sH, w32, lm, lq);

    // node mode: zero this block's agg rows (all reads consumed above).
    if (MODE == 2 && aggOut) {
        int totalF4 = NW * 32 * 32;
        for (int i = tid; i < totalF4; i += NT) {
            int r = i >> 5, c4 = i & 31;
            int row = m0 + r;
            if (row < M)
                *(float4*)(aggOut + (size_t)row * 128 + c4 * 4) = make_float4(0.f, 0.f, 0.f, 0.f);
        }
    }

    // -------- layer 1 --------
    layer128<NT>(acc, Wt1, sH, sW, w32, lm, lq, tid);
    bar_lgkm();
    park(acc, b1, sH, w32, lm, lq);

    // -------- layer 2 --------
    layer128<NT>(acc, Wt2, sH, sW, w32, lm, lq, tid);

    // -------- epilogue --------
    float g_[8], be_[8], b2_[8];
#pragma unroll
    for (int ct = 0; ct < 8; ++ct) {
        g_[ct] = g[ct * 16 + lm]; be_[ct] = be[ct * 16 + lm]; b2_[ct] = b2[ct * 16 + lm];
    }

    if (MODE == 1) {
        // lane's 8 C-rows are 8 CONSECUTIVE sorted slots: one merge run;
        // ef residual written at slot position (skipped when resid==0: dead on last step)
        float run[8];
        int curRcv = -1;
#pragma unroll
        for (int j = 0; j < 8; ++j) {
            int rt = j & 1, reg = j >> 1;
            int rloc = w32 + lq * 8 + j;
            float v[8];
            float s = 0.f;
#pragma unroll
            for (int ct = 0; ct < 8; ++ct) { v[ct] = acc[rt][ct][reg] + b2_[ct]; s += v[ct]; }
            s += __shfl_xor(s, 1); s += __shfl_xor(s, 2);
            s += __shfl_xor(s, 4); s += __shfl_xor(s, 8);
            float mu = s * (1.f / 128.f);
            float q = 0.f;
#pragma unroll
            for (int ct = 0; ct < 8; ++ct) { v[ct] -= mu; q += v[ct] * v[ct]; }
            q += __shfl_xor(q, 1); q += __shfl_xor(q, 2);
            q += __shfl_xor(q, 4); q += __shfl_xor(q, 8);
            float rs = rsqrtf(q * (1.f / 128.f) + 1e-5f);
            int rcv = sRcv[rloc];
            float o[8];
#pragma unroll
            for (int ct = 0; ct < 8; ++ct) {
                o[ct] = v[ct] * rs * g_[ct] + be_[ct];
                if (resid) {
                    size_t gi = (size_t)(m0 + rloc) * 128 + ct * 16 + lm;
                    outF[gi] += o[ct];
                }
            }
            if (rcv != curRcv) {
                if (curRcv >= 0) {
#pragma unroll
                    for (int ct = 0; ct < 8; ++ct)
                        atomicAdd(aggOut + (size_t)curRcv * 128 + ct * 16 + lm, run[ct]);
                }
                curRcv = rcv;
#pragma unroll
                for (int ct = 0; ct < 8; ++ct) run[ct] = o[ct];
            } else {
#pragma unroll
                for (int ct = 0; ct < 8; ++ct) run[ct] += o[ct];
            }
        }
        if (curRcv >= 0) {
#pragma unroll
            for (int ct = 0; ct < 8; ++ct)
                atomicAdd(aggOut + (size_t)curRcv * 128 + ct * 16 + lm, run[ct]);
        }
        return;
    }

    if (MODE == 4) {
        // fused last node step: nf_new = nf_old + LN(...)*g+be, parked bf16 into sH
        // (identical values to the old nfbf path), then run the decoder in-kernel.
#pragma unroll
        for (int rt = 0; rt < 2; ++rt) {
#pragma unroll
            for (int reg = 0; reg < 4; ++reg) {
                int rloc = w32 + rt * 16 + lq * 4 + reg;
                int row = m0 + rloc;
                float v[8];
                float s = 0.f;
#pragma unroll
                for (int ct = 0; ct < 8; ++ct) { v[ct] = acc[rt][ct][reg] + b2_[ct]; s += v[ct]; }
                s += __shfl_xor(s, 1); s += __shfl_xor(s, 2);
                s += __shfl_xor(s, 4); s += __shfl_xor(s, 8);
                float mu = s * (1.f / 128.f);
                float q = 0.f;
#pragma unroll
                for (int ct = 0; ct < 8; ++ct) { v[ct] -= mu; q += v[ct] * v[ct]; }
                q += __shfl_xor(q, 1); q += __shfl_xor(q, 2);
                q += __shfl_xor(q, 4); q += __shfl_xor(q, 8);
                float rs = rsqrtf(q * (1.f / 128.f) + 1e-5f);
#pragma unroll
                for (int ct = 0; ct < 8; ++ct) {
                    float o = v[ct] * rs * g_[ct] + be_[ct];
                    float nfold = (row < M) ? outF[(size_t)row * 128 + ct * 16 + lm] : 0.f;
                    sH[rloc * SH_STRIDE + ct * 16 + lm] = (short)f2bf(nfold + o);
                }
            }
        }
        // decoder layer 0 (relu) and layer 1 (relu)
        layer128<NT>(acc, Wt3, sH, sW, w32, lm, lq, tid);
        bar_lgkm();
        park(acc, db0, sH, w32, lm, lq);
        layer128<NT>(acc, Wt4, sH, sW, w32, lm, lq, tid);
        bar_lgkm();
        park(acc, db1, sH, w32, lm, lq);
        // decoder tail: h2 @ dec_W2[128x3] + db2
#pragma unroll
        for (int t = 0; t < 2; ++t) {
            int idx = t * 64 + lane;
            if (idx < 96) {
                int r = idx / 3, o = idx - r * 3;
                int row = m0 + w32 + r;
                if (row < M) {
                    float s = db2[o];
#pragma unroll
                    for (int kk = 0; kk < 16; ++kk) {
                        bf16x8 h8 = *(const bf16x8*)&sH[(w32 + r) * SH_STRIDE + kk * 8];
#pragma unroll
                        for (int j = 0; j < 8; ++j)
                            s += bf2f(h8[j]) * A0f[(kk * 8 + j) * 3 + o];
                    }
                    decOut[(size_t)row * 3 + o] = s;
                }
            }
        }
        return;
    }

    // MODE 0 / 2: LN + residual + bf16 shadow
#pragma unroll
    for (int rt = 0; rt < 2; ++rt) {
#pragma unroll
        for (int reg = 0; reg < 4; ++reg) {
            int row = m0 + w32 + rt * 16 + lq * 4 + reg;
            float v[8];
            float s = 0.f;
#pragma unroll
            for (int ct = 0; ct < 8; ++ct) { v[ct] = acc[rt][ct][reg] + b2_[ct]; s += v[ct]; }
            s += __shfl_xor(s, 1); s += __shfl_xor(s, 2);
            s += __shfl_xor(s, 4); s += __shfl_xor(s, 8);
            float mu = s * (1.f / 128.f);
            float q = 0.f;
#pragma unroll
            for (int ct = 0; ct < 8; ++ct) { v[ct] -= mu; q += v[ct] * v[ct]; }
            q += __shfl_xor(q, 1); q += __shfl_xor(q, 2);
            q += __shfl_xor(q, 4); q += __shfl_xor(q, 8);
            float rs = rsqrtf(q * (1.f / 128.f) + 1e-5f);
            if (row < M) {
#pragma unroll
                for (int ct = 0; ct < 8; ++ct) {
                    float o = v[ct] * rs * g_[ct] + be_[ct];
                    size_t gi = (size_t)row * 128 + ct * 16 + lm;
                    if (resid) {
                        float ns = outF[gi] + o;
                        outF[gi] = ns;
                        if (outB) outB[gi] = (short)f2bf(ns);
                    } else {
                        outF[gi] = o;
                        if (outB) outB[gi] = (short)f2bf(o);
                    }
                }
            }
        }
    }
}

// ---------------------------------------------------------------------------
__global__ void zero_i(int* __restrict__ p, int n)
{
    int i = blockIdx.x * 256 + threadIdx.x;
    if (i < n) p[i] = 0;
}
__global__ void csr_count(const int* __restrict__ recv, int* __restrict__ cnt, int E)
{
    int i = blockIdx.x * 256 + threadIdx.x;
    if (i < E) atomicAdd(&cnt[recv[i]], 1);
}
__global__ __launch_bounds__(256) void csr_scan(const int* __restrict__ cnt,
                                                int* __restrict__ cursor, int N)
{
    __shared__ int ssum[257];
    const int tid = threadIdx.x;
    const int per = (N + 255) / 256;
    const int lo = tid * per, hi = min(lo + per, N);
    int s = 0;
    for (int i = lo; i < hi; ++i) s += cnt[i];
    ssum[tid] = s;
    __syncthreads();
    if (tid == 0) {
        int run = 0;
        for (int i = 0; i < 256; ++i) { int t = ssum[i]; ssum[i] = run; run += t; }
        ssum[256] = run;
    }
    __syncthreads();
    int run = ssum[tid];
    for (int i = lo; i < hi; ++i) { int c = cnt[i]; cursor[i] = run; run += c; }
}
__global__ void csr_fill(const int* __restrict__ recv, int* __restrict__ cursor,
                         int* __restrict__ eList, int E)
{
    int i = blockIdx.x * 256 + threadIdx.x;
    if (i < E) {
        int pos = atomicAdd(&cursor[recv[i]], 1);
        eList[pos] = i;
    }
}

// ---------------------------------------------------------------------------
struct WtPrep { const float* src; int K; int Kpad; int dstOff; };
struct WtPrepAll { WtPrep m[26]; };

__global__ void wt_prep_kernel(WtPrepAll all, short* __restrict__ dst)
{
    const WtPrep p = all.m[blockIdx.y];
    int total = 128 * p.Kpad;
    int idx = blockIdx.x * 256 + threadIdx.x;
    if (idx >= total) return;
    int n = idx / p.Kpad, k = idx - n * p.Kpad;
    float v = (k < p.K) ? p.src[(size_t)k * 128 + n] : 0.f;
    dst[p.dstOff + idx] = (short)f2bf(v);
}

__global__ void zero_kernel(float4* __restrict__ p, long n4)
{
    long i = (long)blockIdx.x * blockDim.x + threadIdx.x;
    if (i < n4) p[i] = make_float4(0.f, 0.f, 0.f, 0.f);
}

// ---------------------------------------------------------------------------
extern "C" void kernel_launch(void* const* d_in, const int* in_sizes, int n_in,
                              void* d_out, int out_size, void* d_ws, size_t ws_size,
                              hipStream_t stream)
{
    const float* node_x   = (const float*)d_in[0];
    const float* edge_x   = (const float*)d_in[1];
    const float* enc_n_W0 = (const float*)d_in[2];
    const float* enc_n_b0 = (const float*)d_in[3];
    const float* enc_n_W1 = (const float*)d_in[4];
    const float* enc_n_b1 = (const float*)d_in[5];
    const float* enc_n_W2 = (const float*)d_in[6];
    const float* enc_n_b2 = (const float*)d_in[7];
    const float* enc_n_g  = (const float*)d_in[8];
    const float* enc_n_be = (const float*)d_in[9];
    const float* enc_e_W0 = (const float*)d_in[10];
    const float* enc_e_b0 = (const float*)d_in[11];
    const float* enc_e_W1 = (const float*)d_in[12];
    const float* enc_e_b1 = (const float*)d_in[13];
    const float* enc_e_W2 = (const float*)d_in[14];
    const float* enc_e_b2 = (const float*)d_in[15];
    const float* enc_e_g  = (const float*)d_in[16];
    const float* enc_e_be = (const float*)d_in[17];
    const float* gnb_e_W0 = (const float*)d_in[18];
    const float* gnb_e_b0 = (const float*)d_in[19];
    const float* gnb_e_W1 = (const float*)d_in[20];
    const float* gnb_e_b1 = (const float*)d_in[21];
    const float* gnb_e_W2 = (const float*)d_in[22];
    const float* gnb_e_b2 = (const float*)d_in[23];
    const float* gnb_e_g  = (const float*)d_in[24];
    const float* gnb_e_be = (const float*)d_in[25];
    const float* gnb_n_W0 = (const float*)d_in[26];
    const float* gnb_n_b0 = (const float*)d_in[27];
    const float* gnb_n_W1 = (const float*)d_in[28];
    const float* gnb_n_b1 = (const float*)d_in[29];
    const float* gnb_n_W2 = (const float*)d_in[30];
    const float* gnb_n_b2 = (const float*)d_in[31];
    const float* gnb_n_g  = (const float*)d_in[32];
    const float* gnb_n_be = (const float*)d_in[33];
    const float* dec_W0   = (const float*)d_in[34];
    const float* dec_b0   = (const float*)d_in[35];
    const float* dec_W1   = (const float*)d_in[36];
    const float* dec_b1   = (const float*)d_in[37];
    const float* dec_W2   = (const float*)d_in[38];
    const float* dec_b2   = (const float*)d_in[39];
    const int*   senders  = (const int*)d_in[40];
    const int*   receivers= (const int*)d_in[41];
    float* out = (float*)d_out;

    const int N = NN, E = EE;
    const int WT_TOTAL = (32 + 128 + 128 + 32 + 128 + 128 + 3 * (384 + 128 + 128 + 256 + 128 + 128)
                          + 128 + 128) * 128;

    // ---- workspace layout: identical to rounds 6..14 (109.26 MB, known-good) ----
    float* nf   = (float*)d_ws;
    float* agg  = nf + (size_t)N * 128;
    float* ef   = agg + (size_t)N * 128;     // stored in SORTED-SLOT order
    short* nfbf = (short*)(ef + (size_t)E * 128);
    short* wt   = nfbf + (size_t)N * 128;
    int*   eList = (int*)(wt + WT_TOTAL);
    size_t need_sorted = (size_t)((char*)(eList + E) - (char*)d_ws);
    int* cnt    = (int*)agg;
    int* cursor = cnt + N;

    const bool useSorted = (ws_size >= need_sorted);
    const int* eL = useSorted ? eList : nullptr;

    WtPrepAll tbl;
    int nMat = 0, off = 0;
    int o_encn[3], o_ence[3], o_ge0[3], o_ge1[3], o_ge2[3], o_gn0[3], o_gn1[3], o_gn2[3], o_dec[2];
    auto add = [&](const float* src, int K, int Kpad) {
        tbl.m[nMat].src = src; tbl.m[nMat].K = K; tbl.m[nMat].Kpad = Kpad;
        tbl.m[nMat].dstOff = off;
        int r = off; off += 128 * Kpad; ++nMat; return r;
    };
    o_encn[0] = add(enc_n_W0, 12, 32);
    o_encn[1] = add(enc_n_W1, 128, 128);
    o_encn[2] = add(enc_n_W2, 128, 128);
    o_ence[0] = add(enc_e_W0, 7, 32);
    o_ence[1] = add(enc_e_W1, 128, 128);
    o_ence[2] = add(enc_e_W2, 128, 128);
    for (int s = 0; s < 3; ++s) {
        o_ge0[s] = add(gnb_e_W0 + (size_t)s * 384 * 128, 384, 384);
        o_ge1[s] = add(gnb_e_W1 + (size_t)s * 128 * 128, 128, 128);
        o_ge2[s] = add(gnb_e_W2 + (size_t)s * 128 * 128, 128, 128);
        o_gn0[s] = add(gnb_n_W0 + (size_t)s * 256 * 128, 256, 256);
        o_gn1[s] = add(gnb_n_W1 + (size_t)s * 128 * 128, 128, 128);
        o_gn2[s] = add(gnb_n_W2 + (size_t)s * 128 * 128, 128, 128);
    }
    o_dec[0] = add(dec_W0, 128, 128);
    o_dec[1] = add(dec_W1, 128, 128);

    wt_prep_kernel<<<dim3(192, 26), 256, 0, stream>>>(tbl, wt);

    if (useSorted) {
        zero_i<<<dim3((N + 255) / 256), 256, 0, stream>>>(cnt, N);
        csr_count<<<dim3((E + 255) / 256), 256, 0, stream>>>(receivers, cnt, E);
        csr_scan<<<dim3(1), 256, 0, stream>>>(cnt, cursor, N);
        csr_fill<<<dim3((E + 255) / 256), 256, 0, stream>>>(receivers, cursor, eList, E);
    }
    // zero agg once (after csr: cnt/cursor overlay agg); steps 0/1 re-zero in node kernel
    zero_kernel<<<dim3((N * 32 + 255) / 256), 256, 0, stream>>>((float4*)agg, (long)N * 32);

    const dim3 gE(E / 128);                 // NW=4 edge kernels: 1250 blocks
    const dim3 gN2((N + 63) / 64);          // NW=2 node kernels: 313 blocks

    // ---- encoders ----
    gnn_mlp<2, 0><<<gN2, 128, 0, stream>>>(wt + o_encn[0], wt + o_encn[1], wt + o_encn[2],
        nullptr, nullptr,
        enc_n_b0, enc_n_b1, enc_n_b2, nullptr, nullptr, nullptr, enc_n_g, enc_n_be,
        node_x, 12, nullptr, nullptr, nullptr, nullptr, nullptr, nullptr,
        nf, nfbf, nullptr, nullptr, N, 0);
    // edge encoder gathers edge_x[eList[slot]] so ef lands in slot order
    gnn_mlp<4, 0><<<gE, 256, 0, stream>>>(wt + o_ence[0], wt + o_ence[1], wt + o_ence[2],
        nullptr, nullptr,
        enc_e_b0, enc_e_b1, enc_e_b2, nullptr, nullptr, nullptr, enc_e_g, enc_e_be,
        edge_x, 7, nullptr, nullptr, nullptr, eL, nullptr, nullptr,
        ef, nullptr, nullptr, nullptr, E, 0);

    // ---- 3 message-passing steps (last step: dead ef writeback skipped,
    //      node+decoder fused, agg re-zero skipped) ----
    for (int s = 0; s < 3; ++s) {
        const float* eb0 = gnb_e_b0 + (size_t)s * 128;
        const float* eb1 = gnb_e_b1 + (size_t)s * 128;
        const float* eb2 = gnb_e_b2 + (size_t)s * 128;
        const float* eg  = gnb_e_g  + (size_t)s * 128;
        const float* ebe = gnb_e_be + (size_t)s * 128;
        const float* nb0 = gnb_n_b0 + (size_t)s * 128;
        const float* nb1 = gnb_n_b1 + (size_t)s * 128;
        const float* nb2 = gnb_n_b2 + (size_t)s * 128;
        const float* ng  = gnb_n_g  + (size_t)s * 128;
        const float* nbe = gnb_n_be + (size_t)s * 128;
        const bool last = (s == 2);

        gnn_mlp<4, 1><<<gE, 256, 0, stream>>>(wt + o_ge0[s], wt + o_ge1[s], wt + o_ge2[s],
            nullptr, nullptr,
            eb0, eb1, eb2, nullptr, nullptr, nullptr, eg, ebe,
            nullptr, 0, nfbf, ef, nullptr, eL, senders, receivers,
            ef, nullptr, agg, nullptr, E, last ? 0 : 1);
        if (!last) {
            gnn_mlp<2, 2><<<gN2, 128, 0, stream>>>(wt + o_gn0[s], wt + o_gn1[s], wt + o_gn2[s],
                nullptr, nullptr,
                nb0, nb1, nb2, nullptr, nullptr, nullptr, ng, nbe,
                nullptr, 0, nfbf, nullptr, agg, nullptr, nullptr, nullptr,
                nf, nfbf, agg, nullptr, N, 1);
        } else {
            gnn_mlp<2, 4><<<gN2, 128, 0, stream>>>(wt + o_gn0[s], wt + o_gn1[s], wt + o_gn2[s],
                wt + o_dec[0], wt + o_dec[1],
                nb0, nb1, nb2, dec_b0, dec_b1, dec_b2, ng, nbe,
                dec_W2, 0, nfbf, nullptr, agg, nullptr, nullptr, nullptr,
                nf, nullptr, nullptr, out, N, 1);
        }
    }
}

// Round 16
// 648.143 us; speedup vs baseline: 1.0856x; 1.0856x over previous
//
#include <hip/hip_runtime.h>
#include <hip/hip_bf16.h>

#define NN 20000
#define EE 160000

typedef __attribute__((ext_vector_type(8))) short bf16x8;
typedef __attribute__((ext_vector_type(4))) float f32x4;

__device__ __forceinline__ unsigned short f2bf(float f) {
    unsigned int u = __float_as_uint(f);
    u += 0x7FFFu + ((u >> 16) & 1);   // RNE
    return (unsigned short)(u >> 16);
}
__device__ __forceinline__ float bf2f(short s) {
    return __uint_as_float(((unsigned int)(unsigned short)s) << 16);
}
__device__ __forceinline__ bf16x8 pack8(float4 a, float4 b) {
    bf16x8 r;
    r[0] = (short)f2bf(a.x); r[1] = (short)f2bf(a.y);
    r[2] = (short)f2bf(a.z); r[3] = (short)f2bf(a.w);
    r[4] = (short)f2bf(b.x); r[5] = (short)f2bf(b.y);
    r[6] = (short)f2bf(b.z); r[7] = (short)f2bf(b.w);
    return r;
}

#define SH_STRIDE 136
#define SW_STRIDE 56

// barrier that does NOT drain vmcnt (gathers stay in flight)
__device__ __forceinline__ void bar_lgkm() {
    asm volatile("s_waitcnt lgkmcnt(0)\n\ts_barrier" ::: "memory");
}

__device__ __forceinline__ void mfma_sweep_lds(f32x4 (&acc)[2][8], bf16x8 a0, bf16x8 a1,
                                               const short* sWb, int lm, int lq)
{
#pragma unroll
    for (int ct = 0; ct < 8; ++ct) {
        bf16x8 b = *(const bf16x8*)(sWb + (ct * 16 + lm) * SW_STRIDE + lq * 8);
        acc[0][ct] = __builtin_amdgcn_mfma_f32_16x16x32_bf16(a0, b, acc[0][ct], 0, 0, 0);
        acc[1][ct] = __builtin_amdgcn_mfma_f32_16x16x32_bf16(a1, b, acc[1][ct], 0, 0, 0);
    }
}

// W-chunk pipeline: load (registers, issued early) / store (ds_write, later).
template<int NT>
struct WStage { bf16x8 v[512 / NT]; };

template<int NT>
__device__ __forceinline__ void wload(WStage<NT>& ws, const short* __restrict__ Wt,
                                      int Kpad, int k0, int tid)
{
#pragma unroll
    for (int j = 0; j < 256 / NT; ++j) {
        int i = tid + j * NT;
        int r = i >> 1, h = i & 1;
        const short* src = Wt + (size_t)r * Kpad + k0 + h * 16;
        ws.v[2 * j]     = *(const bf16x8*)src;
        ws.v[2 * j + 1] = *(const bf16x8*)(src + 8);
    }
}
template<int NT>
__device__ __forceinline__ void wstore(const WStage<NT>& ws, short* __restrict__ sW, int tid)
{
#pragma unroll
    for (int j = 0; j < 256 / NT; ++j) {
        int i = tid + j * NT;
        int r = i >> 1, h = i & 1;
        short* dst = sW + r * SW_STRIDE + h * 16;
        *(bf16x8*)dst       = ws.v[2 * j];
        *(bf16x8*)(dst + 8) = ws.v[2 * j + 1];
    }
}

__device__ __forceinline__ void zero_acc(f32x4 (&acc)[2][8]) {
#pragma unroll
    for (int i = 0; i < 2; ++i)
#pragma unroll
        for (int j = 0; j < 8; ++j) acc[i][j] = (f32x4)(0.f);
}

__device__ __forceinline__ void park(const f32x4 (&acc)[2][8], const float* __restrict__ bias,
                                     short* __restrict__ sH, int w32, int lm, int lq)
{
#pragma unroll
    for (int ct = 0; ct < 8; ++ct) {
        float bb = bias[ct * 16 + lm];
#pragma unroll
        for (int rt = 0; rt < 2; ++rt) {
            int rbase = w32 + rt * 16 + lq * 4;
#pragma unroll
            for (int reg = 0; reg < 4; ++reg) {
                float v = fmaxf(acc[rt][ct][reg] + bb, 0.f);
                sH[(rbase + reg) * SH_STRIDE + ct * 16 + lm] = (short)f2bf(v);
            }
        }
    }
}

struct Frag {
    bf16x8 a0, a1;
    float4 f0, f1, f2, f3;
    int isF;
};

template<int MODE>
__device__ __forceinline__ void load_frag(Frag& fr, int c,
    const short* __restrict__ nfb, const float* __restrict__ eff,
    const float* __restrict__ aggf,
    int iS0, int iS1, int iR0, int iR1, size_t eO0, size_t eO1,
    int r0m, int r1m, const short* sH, int w32, int lm, int lq)
{
    int kq = lq * 8;
    fr.isF = 0;
    if (MODE == 0) {
        fr.a0 = *(const bf16x8*)&sH[(w32 + lm) * SH_STRIDE + c * 32 + kq];
        fr.a1 = *(const bf16x8*)&sH[(w32 + 16 + lm) * SH_STRIDE + c * 32 + kq];
    } else if (MODE == 1) {
        int seg = c >> 2, kb = (c & 3) * 32 + kq;
        if (seg == 0) {
            fr.a0 = *(const bf16x8*)(nfb + (size_t)iS0 * 128 + kb);
            fr.a1 = *(const bf16x8*)(nfb + (size_t)iS1 * 128 + kb);
        } else if (seg == 1) {
            fr.a0 = *(const bf16x8*)(nfb + (size_t)iR0 * 128 + kb);
            fr.a1 = *(const bf16x8*)(nfb + (size_t)iR1 * 128 + kb);
        } else {
            const float* p0 = eff + eO0 + kb;      // slot-contiguous (ef stored sorted)
            const float* p1 = eff + eO1 + kb;
            fr.f0 = *(const float4*)p0; fr.f1 = *(const float4*)(p0 + 4);
            fr.f2 = *(const float4*)p1; fr.f3 = *(const float4*)(p1 + 4);
            fr.isF = 1;
        }
    } else if (MODE == 2) {
        int seg = c >> 2, kb = (c & 3) * 32 + kq;
        if (seg == 0) {
            fr.a0 = *(const bf16x8*)(nfb + (size_t)r0m * 128 + kb);
            fr.a1 = *(const bf16x8*)(nfb + (size_t)r1m * 128 + kb);
        } else {
            const float* p0 = aggf + (size_t)r0m * 128 + kb;
            const float* p1 = aggf + (size_t)r1m * 128 + kb;
            fr.f0 = *(const float4*)p0; fr.f1 = *(const float4*)(p0 + 4);
            fr.f2 = *(const float4*)p1; fr.f3 = *(const float4*)(p1 + 4);
            fr.isF = 1;
        }
    } else {
        int kb = c * 32 + kq;
        fr.a0 = *(const bf16x8*)(nfb + (size_t)r0m * 128 + kb);
        fr.a1 = *(const bf16x8*)(nfb + (size_t)r1m * 128 + kb);
    }
}

// NW waves per block, 32 rows per wave. MODE compile-time: 0 encoder (eList =
// optional src gather map); 1 edge (sorted slots, ef slot-ordered; RESID=0
// deletes the dead ef writeback at compile time); 2 node (zeroes own agg
// rows); 3 decoder.
template<int NW, int MODE, int RESID>
__global__ __launch_bounds__(NW * 64) void gnn_mlp(
    const short* __restrict__ Wt0,
    const short* __restrict__ Wt1, const short* __restrict__ Wt2,
    const float* __restrict__ b0, const float* __restrict__ b1, const float* __restrict__ b2,
    const float* __restrict__ g, const float* __restrict__ be,
    const float* __restrict__ A0f, int K0,
    const short* __restrict__ nfb,
    const float* __restrict__ eff,
    const float* __restrict__ aggf,
    const int* __restrict__ eList,
    const int* __restrict__ senders, const int* __restrict__ receivers,
    float* __restrict__ outF, short* __restrict__ outB,
    float* __restrict__ aggOut,
    float* __restrict__ decOut,
    int M, int resid)
{
    constexpr int KP0 = (MODE == 1) ? 384 : (MODE == 2) ? 256 : (MODE == 3) ? 128 : 32;
    constexpr int nC0 = KP0 / 32;
    __shared__ short sH[NW * 32 * SH_STRIDE];
    __shared__ short sW[128 * SW_STRIDE];
    __shared__ int sRcv[NW * 32], sSnd[NW * 32];
    const int tid = threadIdx.x;
    const int lane = tid & 63;
    const int w = tid >> 6;
    const int lm = lane & 15;
    const int lq = lane >> 4;
    const int w32 = w * 32;
    const int m0 = blockIdx.x * (NW * 32);
    constexpr int NT = NW * 64;

    if (MODE == 1) {
        if (tid < NW * 32) {
            int slot = m0 + tid;                       // grid exact: slot < E
            int e = eList ? eList[slot] : slot;
            sRcv[tid] = receivers[e];
            sSnd[tid] = senders[e];
        }
        bar_lgkm();
    }

    f32x4 acc[2][8];
    zero_acc(acc);

    // -------- layer 0 (depth-2 gather pipeline, depth-1 W, lgkm barriers) ----
    if (MODE == 0) {
#pragma unroll
        for (int i = 0; i < 16; ++i) {
            int flat = lane + i * 64;
            int r = flat >> 5, k = flat & 31;
            int row = m0 + w32 + r;
            float v = 0.f;
            if (k < K0 && row < M) {
                int src = eList ? eList[row] : row;    // gather source rows (sorted write)
                v = A0f[(size_t)src * K0 + k];
            }
            sH[(w32 + r) * SH_STRIDE + k] = (short)f2bf(v);
        }
    }
    int iS0 = 0, iS1 = 0, iR0 = 0, iR1 = 0;
    size_t eO0 = 0, eO1 = 0;
    if (MODE == 1) {
        // rt-interleaved: MFMA row m of tile rt <-> sorted slot w32 + 2*m + rt.
        int s0 = w32 + 2 * lm, s1 = s0 + 1;
        iS0 = sSnd[s0]; iS1 = sSnd[s1];
        iR0 = sRcv[s0]; iR1 = sRcv[s1];
        eO0 = (size_t)(m0 + s0) * 128;                 // ef is slot-ordered: contiguous
        eO1 = (size_t)(m0 + s1) * 128;
    }
    const int r0m = min(m0 + w32 + lm, M - 1);
    const int r1m = min(m0 + w32 + 16 + lm, M - 1);

    {
        WStage<NT> ws, wsn;
        Frag cur, nx1, nx2;
        wload<NT>(ws, Wt0, KP0, 0, tid);               // W(0) before any gathers
        load_frag<MODE>(cur, 0, nfb, eff, aggf, iS0, iS1, iR0, iR1, eO0, eO1,
                        r0m, r1m, sH, w32, lm, lq);
        if (nC0 > 1)
            load_frag<MODE>(nx1, 1, nfb, eff, aggf, iS0, iS1, iR0, iR1, eO0, eO1,
                            r0m, r1m, sH, w32, lm, lq);
#pragma unroll
        for (int c = 0; c < nC0; ++c) {
            if (c + 1 < nC0)
                wload<NT>(wsn, Wt0, KP0, (c + 1) * 32, tid);
            if (c + 2 < nC0)
                load_frag<MODE>(nx2, c + 2, nfb, eff, aggf, iS0, iS1, iR0, iR1, eO0, eO1,
                                r0m, r1m, sH, w32, lm, lq);
            bar_lgkm();                 // waves done reading previous sW chunk
            wstore<NT>(ws, sW, tid);    // vmcnt targets W(c); frags c+1,c+2 + W(c+1) in flight
            bar_lgkm();                 // chunk staged
            bf16x8 u0, u1;
            if (cur.isF) { u0 = pack8(cur.f0, cur.f1); u1 = pack8(cur.f2, cur.f3); }
            else         { u0 = cur.a0;               u1 = cur.a1; }
            mfma_sweep_lds(acc, u0, u1, sW, lm, lq);
            ws = wsn; cur = nx1; nx1 = nx2;
        }
    }
    bar_lgkm();
    park(acc, b0, sH, w32, lm, lq);

    // node mode: zero this block's agg rows (all reads consumed above).
    if (MODE == 2 && aggOut) {
        int totalF4 = NW * 32 * 32;
        for (int i = tid; i < totalF4; i += NT) {
            int r = i >> 5, c4 = i & 31;
            int row = m0 + r;
            if (row < M)
                *(float4*)(aggOut + (size_t)row * 128 + c4 * 4) = make_float4(0.f, 0.f, 0.f, 0.f);
        }
    }

    // -------- layer 1 (W pipelined) --------
    zero_acc(acc);
    {
        WStage<NT> ws, wsn;
        wload<NT>(ws, Wt1, 128, 0, tid);
#pragma unroll
        for (int c = 0; c < 4; ++c) {
            if (c + 1 < 4) wload<NT>(wsn, Wt1, 128, (c + 1) * 32, tid);
            bf16x8 a0 = *(const bf16x8*)&sH[(w32 + lm) * SH_STRIDE + c * 32 + lq * 8];
            bf16x8 a1 = *(const bf16x8*)&sH[(w32 + 16 + lm) * SH_STRIDE + c * 32 + lq * 8];
            bar_lgkm();
            wstore<NT>(ws, sW, tid);
            bar_lgkm();
            mfma_sweep_lds(acc, a0, a1, sW, lm, lq);
            ws = wsn;
        }
    }
    bar_lgkm();
    park(acc, b1, sH, w32, lm, lq);

    // -------- decoder tail --------
    if (MODE == 3) {
#pragma unroll
        for (int t = 0; t < 2; ++t) {
            int idx = t * 64 + lane;
            if (idx < 96) {
                int r = idx / 3, o = idx - r * 3;
                int row = m0 + w32 + r;
                if (row < M) {
                    float s = b2[o];
#pragma unroll
                    for (int kk = 0; kk < 16; ++kk) {
                        bf16x8 h8 = *(const bf16x8*)&sH[(w32 + r) * SH_STRIDE + kk * 8];
#pragma unroll
                        for (int j = 0; j < 8; ++j)
                            s += bf2f(h8[j]) * A0f[(kk * 8 + j) * 3 + o];
                    }
                    decOut[(size_t)row * 3 + o] = s;
                }
            }
        }
        return;
    }

    // -------- layer 2 (W pipelined) --------
    zero_acc(acc);
    {
        WStage<NT> ws, wsn;
        wload<NT>(ws, Wt2, 128, 0, tid);
#pragma unroll
        for (int c = 0; c < 4; ++c) {
            if (c + 1 < 4) wload<NT>(wsn, Wt2, 128, (c + 1) * 32, tid);
            bf16x8 a0 = *(const bf16x8*)&sH[(w32 + lm) * SH_STRIDE + c * 32 + lq * 8];
            bf16x8 a1 = *(const bf16x8*)&sH[(w32 + 16 + lm) * SH_STRIDE + c * 32 + lq * 8];
            bar_lgkm();
            wstore<NT>(ws, sW, tid);
            bar_lgkm();
            mfma_sweep_lds(acc, a0, a1, sW, lm, lq);
            ws = wsn;
        }
    }

    // -------- epilogue --------
    float g_[8], be_[8], b2_[8];
#pragma unroll
    for (int ct = 0; ct < 8; ++ct) {
        g_[ct] = g[ct * 16 + lm]; be_[ct] = be[ct * 16 + lm]; b2_[ct] = b2[ct * 16 + lm];
    }

    if (MODE == 1) {
        // lane's 8 C-rows are 8 CONSECUTIVE sorted slots: one merge run;
        // ef residual written at slot position (contiguous stream); RESID=0
        // compiles the writeback out entirely (dead on the last step)
        float run[8];
        int curRcv = -1;
#pragma unroll
        for (int j = 0; j < 8; ++j) {
            int rt = j & 1, reg = j >> 1;
            int rloc = w32 + lq * 8 + j;
            float v[8];
            float s = 0.f;
#pragma unroll
            for (int ct = 0; ct < 8; ++ct) { v[ct] = acc[rt][ct][reg] + b2_[ct]; s += v[ct]; }
            s += __shfl_xor(s, 1); s += __shfl_xor(s, 2);
            s += __shfl_xor(s, 4); s += __shfl_xor(s, 8);
            float mu = s * (1.f / 128.f);
            float q = 0.f;
#pragma unroll
            for (int ct = 0; ct < 8; ++ct) { v[ct] -= mu; q += v[ct] * v[ct]; }
            q += __shfl_xor(q, 1); q += __shfl_xor(q, 2);
            q += __shfl_xor(q, 4); q += __shfl_xor(q, 8);
            float rs = rsqrtf(q * (1.f / 128.f) + 1e-5f);
            int rcv = sRcv[rloc];
            float o[8];
#pragma unroll
            for (int ct = 0; ct < 8; ++ct) {
                o[ct] = v[ct] * rs * g_[ct] + be_[ct];
                if (RESID) {
                    size_t gi = (size_t)(m0 + rloc) * 128 + ct * 16 + lm;
                    outF[gi] += o[ct];                  // ef residual, slot-ordered
                }
            }
            if (rcv != curRcv) {
                if (curRcv >= 0) {
#pragma unroll
                    for (int ct = 0; ct < 8; ++ct)
                        atomicAdd(aggOut + (size_t)curRcv * 128 + ct * 16 + lm, run[ct]);
                }
                curRcv = rcv;
#pragma unroll
                for (int ct = 0; ct < 8; ++ct) run[ct] = o[ct];
            } else {
#pragma unroll
                for (int ct = 0; ct < 8; ++ct) run[ct] += o[ct];
            }
        }
        if (curRcv >= 0) {
#pragma unroll
            for (int ct = 0; ct < 8; ++ct)
                atomicAdd(aggOut + (size_t)curRcv * 128 + ct * 16 + lm, run[ct]);
        }
    } else {
#pragma unroll
        for (int rt = 0; rt < 2; ++rt) {
#pragma unroll
            for (int reg = 0; reg < 4; ++reg) {
                int row = m0 + w32 + rt * 16 + lq * 4 + reg;
                float v[8];
                float s = 0.f;
#pragma unroll
                for (int ct = 0; ct < 8; ++ct) { v[ct] = acc[rt][ct][reg] + b2_[ct]; s += v[ct]; }
                s += __shfl_xor(s, 1); s += __shfl_xor(s, 2);
                s += __shfl_xor(s, 4); s += __shfl_xor(s, 8);
                float mu = s * (1.f / 128.f);
                float q = 0.f;
#pragma unroll
                for (int ct = 0; ct < 8; ++ct) { v[ct] -= mu; q += v[ct] * v[ct]; }
                q += __shfl_xor(q, 1); q += __shfl_xor(q, 2);
                q += __shfl_xor(q, 4); q += __shfl_xor(q, 8);
                float rs = rsqrtf(q * (1.f / 128.f) + 1e-5f);
                if (row < M) {
#pragma unroll
                    for (int ct = 0; ct < 8; ++ct) {
                        float o = v[ct] * rs * g_[ct] + be_[ct];
                        size_t gi = (size_t)row * 128 + ct * 16 + lm;
                        if (resid) {
                            float ns = outF[gi] + o;
                            outF[gi] = ns;
                            if (outB) outB[gi] = (short)f2bf(ns);
                        } else {
                            outF[gi] = o;
                            if (outB) outB[gi] = (short)f2bf(o);
                        }
                    }
                }
            }
        }
    }
}

// ---------------------------------------------------------------------------
__global__ void zero_i(int* __restrict__ p, int n)
{
    int i = blockIdx.x * 256 + threadIdx.x;
    if (i < n) p[i] = 0;
}
__global__ void csr_count(const int* __restrict__ recv, int* __restrict__ cnt, int E)
{
    int i = blockIdx.x * 256 + threadIdx.x;
    if (i < E) atomicAdd(&cnt[recv[i]], 1);
}
__global__ __launch_bounds__(256) void csr_scan(const int* __restrict__ cnt,
                                                int* __restrict__ cursor, int N)
{
    __shared__ int ssum[257];
    const int tid = threadIdx.x;
    const int per = (N + 255) / 256;
    const int lo = tid * per, hi = min(lo + per, N);
    int s = 0;
    for (int i = lo; i < hi; ++i) s += cnt[i];
    ssum[tid] = s;
    __syncthreads();
    if (tid == 0) {
        int run = 0;
        for (int i = 0; i < 256; ++i) { int t = ssum[i]; ssum[i] = run; run += t; }
        ssum[256] = run;
    }
    __syncthreads();
    int run = ssum[tid];
    for (int i = lo; i < hi; ++i) { int c = cnt[i]; cursor[i] = run; run += c; }
}
__global__ void csr_fill(const int* __restrict__ recv, int* __restrict__ cursor,
                         int* __restrict__ eList, int E)
{
    int i = blockIdx.x * 256 + threadIdx.x;
    if (i < E) {
        int pos = atomicAdd(&cursor[recv[i]], 1);
        eList[pos] = i;
    }
}

// ---------------------------------------------------------------------------
struct WtPrep { const float* src; int K; int Kpad; int dstOff; };
struct WtPrepAll { WtPrep m[26]; };

__global__ void wt_prep_kernel(WtPrepAll all, short* __restrict__ dst)
{
    const WtPrep p = all.m[blockIdx.y];
    int total = 128 * p.Kpad;
    int idx = blockIdx.x * 256 + threadIdx.x;
    if (idx >= total) return;
    int n = idx / p.Kpad, k = idx - n * p.Kpad;
    float v = (k < p.K) ? p.src[(size_t)k * 128 + n] : 0.f;
    dst[p.dstOff + idx] = (short)f2bf(v);
}

__global__ void zero_kernel(float4* __restrict__ p, long n4)
{
    long i = (long)blockIdx.x * blockDim.x + threadIdx.x;
    if (i < n4) p[i] = make_float4(0.f, 0.f, 0.f, 0.f);
}

// ---------------------------------------------------------------------------
extern "C" void kernel_launch(void* const* d_in, const int* in_sizes, int n_in,
                              void* d_out, int out_size, void* d_ws, size_t ws_size,
                              hipStream_t stream)
{
    const float* node_x   = (const float*)d_in[0];
    const float* edge_x   = (const float*)d_in[1];
    const float* enc_n_W0 = (const float*)d_in[2];
    const float* enc_n_b0 = (const float*)d_in[3];
    const float* enc_n_W1 = (const float*)d_in[4];
    const float* enc_n_b1 = (const float*)d_in[5];
    const float* enc_n_W2 = (const float*)d_in[6];
    const float* enc_n_b2 = (const float*)d_in[7];
    const float* enc_n_g  = (const float*)d_in[8];
    const float* enc_n_be = (const float*)d_in[9];
    const float* enc_e_W0 = (const float*)d_in[10];
    const float* enc_e_b0 = (const float*)d_in[11];
    const float* enc_e_W1 = (const float*)d_in[12];
    const float* enc_e_b1 = (const float*)d_in[13];
    const float* enc_e_W2 = (const float*)d_in[14];
    const float* enc_e_b2 = (const float*)d_in[15];
    const float* enc_e_g  = (const float*)d_in[16];
    const float* enc_e_be = (const float*)d_in[17];
    const float* gnb_e_W0 = (const float*)d_in[18];
    const float* gnb_e_b0 = (const float*)d_in[19];
    const float* gnb_e_W1 = (const float*)d_in[20];
    const float* gnb_e_b1 = (const float*)d_in[21];
    const float* gnb_e_W2 = (const float*)d_in[22];
    const float* gnb_e_b2 = (const float*)d_in[23];
    const float* gnb_e_g  = (const float*)d_in[24];
    const float* gnb_e_be = (const float*)d_in[25];
    const float* gnb_n_W0 = (const float*)d_in[26];
    const float* gnb_n_b0 = (const float*)d_in[27];
    const float* gnb_n_W1 = (const float*)d_in[28];
    const float* gnb_n_b1 = (const float*)d_in[29];
    const float* gnb_n_W2 = (const float*)d_in[30];
    const float* gnb_n_b2 = (const float*)d_in[31];
    const float* gnb_n_g  = (const float*)d_in[32];
    const float* gnb_n_be = (const float*)d_in[33];
    const float* dec_W0   = (const float*)d_in[34];
    const float* dec_b0   = (const float*)d_in[35];
    const float* dec_W1   = (const float*)d_in[36];
    const float* dec_b1   = (const float*)d_in[37];
    const float* dec_W2   = (const float*)d_in[38];
    const float* dec_b2   = (const float*)d_in[39];
    const int*   senders  = (const int*)d_in[40];
    const int*   receivers= (const int*)d_in[41];
    float* out = (float*)d_out;

    const int N = NN, E = EE;
    const int WT_TOTAL = (32 + 128 + 128 + 32 + 128 + 128 + 3 * (384 + 128 + 128 + 256 + 128 + 128)
                          + 128 + 128) * 128;

    // ---- workspace layout: identical to rounds 6..14 (109.26 MB, known-good) ----
    float* nf   = (float*)d_ws;
    float* agg  = nf + (size_t)N * 128;
    float* ef   = agg + (size_t)N * 128;     // stored in SORTED-SLOT order
    short* nfbf = (short*)(ef + (size_t)E * 128);
    short* wt   = nfbf + (size_t)N * 128;
    int*   eList = (int*)(wt + WT_TOTAL);
    size_t need_sorted = (size_t)((char*)(eList + E) - (char*)d_ws);
    int* cnt    = (int*)agg;
    int* cursor = cnt + N;

    const bool useSorted = (ws_size >= need_sorted);
    const int* eL = useSorted ? eList : nullptr;

    WtPrepAll tbl;
    int nMat = 0, off = 0;
    int o_encn[3], o_ence[3], o_ge0[3], o_ge1[3], o_ge2[3], o_gn0[3], o_gn1[3], o_gn2[3], o_dec[2];
    auto add = [&](const float* src, int K, int Kpad) {
        tbl.m[nMat].src = src; tbl.m[nMat].K = K; tbl.m[nMat].Kpad = Kpad;
        tbl.m[nMat].dstOff = off;
        int r = off; off += 128 * Kpad; ++nMat; return r;
    };
    o_encn[0] = add(enc_n_W0, 12, 32);
    o_encn[1] = add(enc_n_W1, 128, 128);
    o_encn[2] = add(enc_n_W2, 128, 128);
    o_ence[0] = add(enc_e_W0, 7, 32);
    o_ence[1] = add(enc_e_W1, 128, 128);
    o_ence[2] = add(enc_e_W2, 128, 128);
    for (int s = 0; s < 3; ++s) {
        o_ge0[s] = add(gnb_e_W0 + (size_t)s * 384 * 128, 384, 384);
        o_ge1[s] = add(gnb_e_W1 + (size_t)s * 128 * 128, 128, 128);
        o_ge2[s] = add(gnb_e_W2 + (size_t)s * 128 * 128, 128, 128);
        o_gn0[s] = add(gnb_n_W0 + (size_t)s * 256 * 128, 256, 256);
        o_gn1[s] = add(gnb_n_W1 + (size_t)s * 128 * 128, 128, 128);
        o_gn2[s] = add(gnb_n_W2 + (size_t)s * 128 * 128, 128, 128);
    }
    o_dec[0] = add(dec_W0, 128, 128);
    o_dec[1] = add(dec_W1, 128, 128);

    wt_prep_kernel<<<dim3(192, 26), 256, 0, stream>>>(tbl, wt);

    if (useSorted) {
        zero_i<<<dim3((N + 255) / 256), 256, 0, stream>>>(cnt, N);
        csr_count<<<dim3((E + 255) / 256), 256, 0, stream>>>(receivers, cnt, E);
        csr_scan<<<dim3(1), 256, 0, stream>>>(cnt, cursor, N);
        csr_fill<<<dim3((E + 255) / 256), 256, 0, stream>>>(receivers, cursor, eList, E);
    }
    // zero agg once (after csr: cnt/cursor overlay agg); steps re-zero in node kernel
    zero_kernel<<<dim3((N * 32 + 255) / 256), 256, 0, stream>>>((float4*)agg, (long)N * 32);

    const dim3 gE(E / 128);                 // NW=4 edge kernels: 1250 blocks
    const dim3 gN2((N + 63) / 64);          // NW=2 node kernels: 313 blocks

    // ---- encoders ----
    gnn_mlp<2, 0, 1><<<gN2, 128, 0, stream>>>(wt + o_encn[0], wt + o_encn[1], wt + o_encn[2],
        enc_n_b0, enc_n_b1, enc_n_b2, enc_n_g, enc_n_be,
        node_x, 12, nullptr, nullptr, nullptr, nullptr, nullptr, nullptr,
        nf, nfbf, nullptr, nullptr, N, 0);
    // edge encoder gathers edge_x[eList[slot]] so ef lands in slot order
    gnn_mlp<4, 0, 1><<<gE, 256, 0, stream>>>(wt + o_ence[0], wt + o_ence[1], wt + o_ence[2],
        enc_e_b0, enc_e_b1, enc_e_b2, enc_e_g, enc_e_be,
        edge_x, 7, nullptr, nullptr, nullptr, eL, nullptr, nullptr,
        ef, nullptr, nullptr, nullptr, E, 0);

    // ---- 3 message-passing steps (last edge step: dead ef writeback deleted) ----
    for (int s = 0; s < 3; ++s) {
        const float* eb0 = gnb_e_b0 + (size_t)s * 128;
        const float* eb1 = gnb_e_b1 + (size_t)s * 128;
        const float* eb2 = gnb_e_b2 + (size_t)s * 128;
        const float* eg  = gnb_e_g  + (size_t)s * 128;
        const float* ebe = gnb_e_be + (size_t)s * 128;
        const float* nb0 = gnb_n_b0 + (size_t)s * 128;
        const float* nb1 = gnb_n_b1 + (size_t)s * 128;
        const float* nb2 = gnb_n_b2 + (size_t)s * 128;
        const float* ng  = gnb_n_g  + (size_t)s * 128;
        const float* nbe = gnb_n_be + (size_t)s * 128;

        if (s < 2) {
            gnn_mlp<4, 1, 1><<<gE, 256, 0, stream>>>(wt + o_ge0[s], wt + o_ge1[s], wt + o_ge2[s],
                eb0, eb1, eb2, eg, ebe,
                nullptr, 0, nfbf, ef, nullptr, eL, senders, receivers,
                ef, nullptr, agg, nullptr, E, 1);
        } else {
            gnn_mlp<4, 1, 0><<<gE, 256, 0, stream>>>(wt + o_ge0[s], wt + o_ge1[s], wt + o_ge2[s],
                eb0, eb1, eb2, eg, ebe,
                nullptr, 0, nfbf, ef, nullptr, eL, senders, receivers,
                ef, nullptr, agg, nullptr, E, 1);
        }
        gnn_mlp<2, 2, 1><<<gN2, 128, 0, stream>>>(wt + o_gn0[s], wt + o_gn1[s], wt + o_gn2[s],
            nb0, nb1, nb2, ng, nbe,
            nullptr, 0, nfbf, nullptr, agg, nullptr, nullptr, nullptr,
            nf, nfbf, agg, nullptr, N, 1);
    }

    // ---- decoder ----
    gnn_mlp<2, 3, 1><<<gN2, 128, 0, stream>>>(wt + o_dec[0], wt + o_dec[1], nullptr,
        dec_b0, dec_b1, dec_b2, nullptr, nullptr,
        dec_W2, 0, nfbf, nullptr, nullptr, nullptr, nullptr, nullptr,
        nullptr, nullptr, nullptr, out, N, 0);
}

// Round 17
// 646.099 us; speedup vs baseline: 1.0890x; 1.0032x over previous
//
#include <hip/hip_runtime.h>
#include <hip/hip_bf16.h>

#define NN 20000
#define EE 160000

typedef __attribute__((ext_vector_type(8))) short bf16x8;
typedef __attribute__((ext_vector_type(4))) float f32x4;

__device__ __forceinline__ unsigned short f2bf(float f) {
    unsigned int u = __float_as_uint(f);
    u += 0x7FFFu + ((u >> 16) & 1);   // RNE
    return (unsigned short)(u >> 16);
}
__device__ __forceinline__ float bf2f(short s) {
    return __uint_as_float(((unsigned int)(unsigned short)s) << 16);
}
__device__ __forceinline__ bf16x8 pack8(float4 a, float4 b) {
    bf16x8 r;
    r[0] = (short)f2bf(a.x); r[1] = (short)f2bf(a.y);
    r[2] = (short)f2bf(a.z); r[3] = (short)f2bf(a.w);
    r[4] = (short)f2bf(b.x); r[5] = (short)f2bf(b.y);
    r[6] = (short)f2bf(b.z); r[7] = (short)f2bf(b.w);
    return r;
}

#define SH_STRIDE 136
#define SW_STRIDE 56
// edge64 kernel strides (LDS = 33792 + 18432 + 1024 = 53248 B -> exactly 3 blocks/CU)
#define SH64 132
#define SW64 72

// barrier that does NOT drain vmcnt (gathers stay in flight)
__device__ __forceinline__ void bar_lgkm() {
    asm volatile("s_waitcnt lgkmcnt(0)\n\ts_barrier" ::: "memory");
}

__device__ __forceinline__ void mfma_sweep_lds(f32x4 (&acc)[2][8], bf16x8 a0, bf16x8 a1,
                                               const short* sWb, int lm, int lq)
{
#pragma unroll
    for (int ct = 0; ct < 8; ++ct) {
        bf16x8 b = *(const bf16x8*)(sWb + (ct * 16 + lm) * SW_STRIDE + lq * 8);
        acc[0][ct] = __builtin_amdgcn_mfma_f32_16x16x32_bf16(a0, b, acc[0][ct], 0, 0, 0);
        acc[1][ct] = __builtin_amdgcn_mfma_f32_16x16x32_bf16(a1, b, acc[1][ct], 0, 0, 0);
    }
}

// 64-k variant: B from sW64 at column offset colOff (shorts)
__device__ __forceinline__ void mfma_sweep64(f32x4 (&acc)[2][8], bf16x8 a0, bf16x8 a1,
                                             const short* sWb, int colOff, int lm)
{
#pragma unroll
    for (int ct = 0; ct < 8; ++ct) {
        bf16x8 b = *(const bf16x8*)(sWb + (ct * 16 + lm) * SW64 + colOff);
        acc[0][ct] = __builtin_amdgcn_mfma_f32_16x16x32_bf16(a0, b, acc[0][ct], 0, 0, 0);
        acc[1][ct] = __builtin_amdgcn_mfma_f32_16x16x32_bf16(a1, b, acc[1][ct], 0, 0, 0);
    }
}

// W-chunk pipeline: load (registers, issued early) / store (ds_write, later).
template<int NT>
struct WStage { bf16x8 v[512 / NT]; };

template<int NT>
__device__ __forceinline__ void wload(WStage<NT>& ws, const short* __restrict__ Wt,
                                      int Kpad, int k0, int tid)
{
#pragma unroll
    for (int j = 0; j < 256 / NT; ++j) {
        int i = tid + j * NT;
        int r = i >> 1, h = i & 1;
        const short* src = Wt + (size_t)r * Kpad + k0 + h * 16;
        ws.v[2 * j]     = *(const bf16x8*)src;
        ws.v[2 * j + 1] = *(const bf16x8*)(src + 8);
    }
}
template<int NT>
__device__ __forceinline__ void wstore(const WStage<NT>& ws, short* __restrict__ sW, int tid)
{
#pragma unroll
    for (int j = 0; j < 256 / NT; ++j) {
        int i = tid + j * NT;
        int r = i >> 1, h = i & 1;
        short* dst = sW + r * SW_STRIDE + h * 16;
        *(bf16x8*)dst       = ws.v[2 * j];
        *(bf16x8*)(dst + 8) = ws.v[2 * j + 1];
    }
}

// 64-k W stage (NT=256 fixed): 128 rows x 64 k, 4 bf16x8/thread
struct WStage64 { bf16x8 v[4]; };
__device__ __forceinline__ void wload64(WStage64& ws, const short* __restrict__ Wt,
                                        int Kpad, int k0, int tid)
{
#pragma unroll
    for (int j = 0; j < 4; ++j) {
        int i = tid + j * 256;
        int r = i >> 3, h = i & 7;
        ws.v[j] = *(const bf16x8*)(Wt + (size_t)r * Kpad + k0 + h * 8);
    }
}
__device__ __forceinline__ void wstore64(const WStage64& ws, short* __restrict__ sW, int tid)
{
#pragma unroll
    for (int j = 0; j < 4; ++j) {
        int i = tid + j * 256;
        int r = i >> 3, h = i & 7;
        *(bf16x8*)(sW + r * SW64 + h * 8) = ws.v[j];
    }
}

__device__ __forceinline__ void zero_acc(f32x4 (&acc)[2][8]) {
#pragma unroll
    for (int i = 0; i < 2; ++i)
#pragma unroll
        for (int j = 0; j < 8; ++j) acc[i][j] = (f32x4)(0.f);
}

__device__ __forceinline__ void park(const f32x4 (&acc)[2][8], const float* __restrict__ bias,
                                     short* __restrict__ sH, int w32, int lm, int lq)
{
#pragma unroll
    for (int ct = 0; ct < 8; ++ct) {
        float bb = bias[ct * 16 + lm];
#pragma unroll
        for (int rt = 0; rt < 2; ++rt) {
            int rbase = w32 + rt * 16 + lq * 4;
#pragma unroll
            for (int reg = 0; reg < 4; ++reg) {
                float v = fmaxf(acc[rt][ct][reg] + bb, 0.f);
                sH[(rbase + reg) * SH_STRIDE + ct * 16 + lm] = (short)f2bf(v);
            }
        }
    }
}

__device__ __forceinline__ void park64(const f32x4 (&acc)[2][8], const float* __restrict__ bias,
                                       short* __restrict__ sH, int w32, int lm, int lq)
{
#pragma unroll
    for (int ct = 0; ct < 8; ++ct) {
        float bb = bias[ct * 16 + lm];
#pragma unroll
        for (int rt = 0; rt < 2; ++rt) {
            int rbase = w32 + rt * 16 + lq * 4;
#pragma unroll
            for (int reg = 0; reg < 4; ++reg) {
                float v = fmaxf(acc[rt][ct][reg] + bb, 0.f);
                sH[(rbase + reg) * SH64 + ct * 16 + lm] = (short)f2bf(v);
            }
        }
    }
}

struct Frag {
    bf16x8 a0, a1;
    float4 f0, f1, f2, f3;
    int isF;
};

template<int MODE>
__device__ __forceinline__ void load_frag(Frag& fr, int c,
    const short* __restrict__ nfb, const float* __restrict__ eff,
    const float* __restrict__ aggf,
    int iS0, int iS1, int iR0, int iR1, size_t eO0, size_t eO1,
    int r0m, int r1m, const short* sH, int w32, int lm, int lq)
{
    int kq = lq * 8;
    fr.isF = 0;
    if (MODE == 0) {
        fr.a0 = *(const bf16x8*)&sH[(w32 + lm) * SH_STRIDE + c * 32 + kq];
        fr.a1 = *(const bf16x8*)&sH[(w32 + 16 + lm) * SH_STRIDE + c * 32 + kq];
    } else if (MODE == 2) {
        int seg = c >> 2, kb = (c & 3) * 32 + kq;
        if (seg == 0) {
            fr.a0 = *(const bf16x8*)(nfb + (size_t)r0m * 128 + kb);
            fr.a1 = *(const bf16x8*)(nfb + (size_t)r1m * 128 + kb);
        } else {
            const float* p0 = aggf + (size_t)r0m * 128 + kb;
            const float* p1 = aggf + (size_t)r1m * 128 + kb;
            fr.f0 = *(const float4*)p0; fr.f1 = *(const float4*)(p0 + 4);
            fr.f2 = *(const float4*)p1; fr.f3 = *(const float4*)(p1 + 4);
            fr.isF = 1;
        }
    } else {
        int kb = c * 32 + kq;
        fr.a0 = *(const bf16x8*)(nfb + (size_t)r0m * 128 + kb);
        fr.a1 = *(const bf16x8*)(nfb + (size_t)r1m * 128 + kb);
    }
}

// 64-k fragment for the edge kernel: 2 row-tiles x 2 k-halves
struct Frag64 {
    bf16x8 a[4];          // [row][half] for bf16 segs
    float4 f[8];          // fp32 ef: f[0..3]=row0 (h0,h0+,h1,h1+), f[4..7]=row1
    int isF;
};

__device__ __forceinline__ void load_frag64(Frag64& fr, int c,
    const short* __restrict__ nfb, const float* __restrict__ eff,
    int iS0, int iS1, int iR0, int iR1, size_t eO0, size_t eO1, int lq)
{
    int kb = (c & 1) * 64 + lq * 8;
    int seg = c >> 1;
    fr.isF = 0;
    if (seg == 0) {
        fr.a[0] = *(const bf16x8*)(nfb + (size_t)iS0 * 128 + kb);
        fr.a[1] = *(const bf16x8*)(nfb + (size_t)iS1 * 128 + kb);
        fr.a[2] = *(const bf16x8*)(nfb + (size_t)iS0 * 128 + kb + 32);
        fr.a[3] = *(const bf16x8*)(nfb + (size_t)iS1 * 128 + kb + 32);
    } else if (seg == 1) {
        fr.a[0] = *(const bf16x8*)(nfb + (size_t)iR0 * 128 + kb);
        fr.a[1] = *(const bf16x8*)(nfb + (size_t)iR1 * 128 + kb);
        fr.a[2] = *(const bf16x8*)(nfb + (size_t)iR0 * 128 + kb + 32);
        fr.a[3] = *(const bf16x8*)(nfb + (size_t)iR1 * 128 + kb + 32);
    } else {
        const float* p0 = eff + eO0 + kb;
        const float* p1 = eff + eO1 + kb;
        fr.f[0] = *(const float4*)p0;        fr.f[1] = *(const float4*)(p0 + 4);
        fr.f[2] = *(const float4*)(p0 + 32); fr.f[3] = *(const float4*)(p0 + 36);
        fr.f[4] = *(const float4*)p1;        fr.f[5] = *(const float4*)(p1 + 4);
        fr.f[6] = *(const float4*)(p1 + 32); fr.f[7] = *(const float4*)(p1 + 36);
        fr.isF = 1;
    }
}

// ---------------------------------------------------------------------------
// Edge MLP kernel, 64-k chunks (half the barriers of the 32-k structure).
// NW=4 fixed. RESID=0 deletes the dead ef writeback (last step).
// ---------------------------------------------------------------------------
template<int RESID>
__global__ __launch_bounds__(256) void gnn_edge64(
    const short* __restrict__ Wt0,
    const short* __restrict__ Wt1, const short* __restrict__ Wt2,
    const float* __restrict__ b0, const float* __restrict__ b1, const float* __restrict__ b2,
    const float* __restrict__ g, const float* __restrict__ be,
    const short* __restrict__ nfb,
    const float* __restrict__ eff,
    const int* __restrict__ eList,
    const int* __restrict__ senders, const int* __restrict__ receivers,
    float* __restrict__ outF, float* __restrict__ aggOut)
{
    __shared__ short sH[128 * SH64];
    __shared__ short sW[128 * SW64];
    __shared__ int sRcv[128], sSnd[128];
    const int tid = threadIdx.x;
    const int lane = tid & 63;
    const int w = tid >> 6;
    const int lm = lane & 15;
    const int lq = lane >> 4;
    const int w32 = w * 32;
    const int m0 = blockIdx.x * 128;

    if (tid < 128) {
        int slot = m0 + tid;                       // grid exact: slot < E
        int e = eList ? eList[slot] : slot;
        sRcv[tid] = receivers[e];
        sSnd[tid] = senders[e];
    }
    bar_lgkm();

    f32x4 acc[2][8];
    zero_acc(acc);

    // rt-interleaved: MFMA row m of tile rt <-> sorted slot w32 + 2*m + rt.
    const int s0 = w32 + 2 * lm, s1 = s0 + 1;
    const int iS0 = sSnd[s0], iS1 = sSnd[s1];
    const int iR0 = sRcv[s0], iR1 = sRcv[s1];
    const size_t eO0 = (size_t)(m0 + s0) * 128;
    const size_t eO1 = (size_t)(m0 + s1) * 128;

    // -------- layer 0: K=384 in 6 chunks of 64 --------
    {
        WStage64 ws, wsn;
        Frag64 cur, nxt;
        wload64(ws, Wt0, 384, 0, tid);
        load_frag64(cur, 0, nfb, eff, iS0, iS1, iR0, iR1, eO0, eO1, lq);
#pragma unroll
        for (int c = 0; c < 6; ++c) {
            if (c + 1 < 6) {
                wload64(wsn, Wt0, 384, (c + 1) * 64, tid);
                load_frag64(nxt, c + 1, nfb, eff, iS0, iS1, iR0, iR1, eO0, eO1, lq);
            }
            bar_lgkm();
            wstore64(ws, sW, tid);
            bar_lgkm();
            bf16x8 u0h0, u1h0, u0h1, u1h1;
            if (cur.isF) {
                u0h0 = pack8(cur.f[0], cur.f[1]); u0h1 = pack8(cur.f[2], cur.f[3]);
                u1h0 = pack8(cur.f[4], cur.f[5]); u1h1 = pack8(cur.f[6], cur.f[7]);
            } else {
                u0h0 = cur.a[0]; u1h0 = cur.a[1]; u0h1 = cur.a[2]; u1h1 = cur.a[3];
            }
            mfma_sweep64(acc, u0h0, u1h0, sW, lq * 8, lm);
            mfma_sweep64(acc, u0h1, u1h1, sW, 32 + lq * 8, lm);
            ws = wsn; cur = nxt;
        }
    }
    bar_lgkm();
    park64(acc, b0, sH, w32, lm, lq);

    // -------- layer 1: 2 chunks of 64 --------
    zero_acc(acc);
    {
        WStage64 ws, wsn;
        wload64(ws, Wt1, 128, 0, tid);
#pragma unroll
        for (int c = 0; c < 2; ++c) {
            if (c == 0) wload64(wsn, Wt1, 128, 64, tid);
            bf16x8 a0h0 = *(const bf16x8*)&sH[(w32 + lm) * SH64 + c * 64 + lq * 8];
            bf16x8 a1h0 = *(const bf16x8*)&sH[(w32 + 16 + lm) * SH64 + c * 64 + lq * 8];
            bf16x8 a0h1 = *(const bf16x8*)&sH[(w32 + lm) * SH64 + c * 64 + 32 + lq * 8];
            bf16x8 a1h1 = *(const bf16x8*)&sH[(w32 + 16 + lm) * SH64 + c * 64 + 32 + lq * 8];
            bar_lgkm();
            wstore64(ws, sW, tid);
            bar_lgkm();
            mfma_sweep64(acc, a0h0, a1h0, sW, lq * 8, lm);
            mfma_sweep64(acc, a0h1, a1h1, sW, 32 + lq * 8, lm);
            ws = wsn;
        }
    }
    bar_lgkm();
    park64(acc, b1, sH, w32, lm, lq);

    // -------- layer 2: 2 chunks of 64 --------
    zero_acc(acc);
    {
        WStage64 ws, wsn;
        wload64(ws, Wt2, 128, 0, tid);
#pragma unroll
        for (int c = 0; c < 2; ++c) {
            if (c == 0) wload64(wsn, Wt2, 128, 64, tid);
            bf16x8 a0h0 = *(const bf16x8*)&sH[(w32 + lm) * SH64 + c * 64 + lq * 8];
            bf16x8 a1h0 = *(const bf16x8*)&sH[(w32 + 16 + lm) * SH64 + c * 64 + lq * 8];
            bf16x8 a0h1 = *(const bf16x8*)&sH[(w32 + lm) * SH64 + c * 64 + 32 + lq * 8];
            bf16x8 a1h1 = *(const bf16x8*)&sH[(w32 + 16 + lm) * SH64 + c * 64 + 32 + lq * 8];
            bar_lgkm();
            wstore64(ws, sW, tid);
            bar_lgkm();
            mfma_sweep64(acc, a0h0, a1h0, sW, lq * 8, lm);
            mfma_sweep64(acc, a0h1, a1h1, sW, 32 + lq * 8, lm);
            ws = wsn;
        }
    }

    // -------- epilogue: LN + (RESID ? ef writeback) + merged-run atomics ----
    float g_[8], be_[8], b2_[8];
#pragma unroll
    for (int ct = 0; ct < 8; ++ct) {
        g_[ct] = g[ct * 16 + lm]; be_[ct] = be[ct * 16 + lm]; b2_[ct] = b2[ct * 16 + lm];
    }
    float run[8];
    int curRcv = -1;
#pragma unroll
    for (int j = 0; j < 8; ++j) {
        int rt = j & 1, reg = j >> 1;
        int rloc = w32 + lq * 8 + j;
        float v[8];
        float s = 0.f;
#pragma unroll
        for (int ct = 0; ct < 8; ++ct) { v[ct] = acc[rt][ct][reg] + b2_[ct]; s += v[ct]; }
        s += __shfl_xor(s, 1); s += __shfl_xor(s, 2);
        s += __shfl_xor(s, 4); s += __shfl_xor(s, 8);
        float mu = s * (1.f / 128.f);
        float q = 0.f;
#pragma unroll
        for (int ct = 0; ct < 8; ++ct) { v[ct] -= mu; q += v[ct] * v[ct]; }
        q += __shfl_xor(q, 1); q += __shfl_xor(q, 2);
        q += __shfl_xor(q, 4); q += __shfl_xor(q, 8);
        float rs = rsqrtf(q * (1.f / 128.f) + 1e-5f);
        int rcv = sRcv[rloc];
        float o[8];
#pragma unroll
        for (int ct = 0; ct < 8; ++ct) {
            o[ct] = v[ct] * rs * g_[ct] + be_[ct];
            if (RESID) {
                size_t gi = (size_t)(m0 + rloc) * 128 + ct * 16 + lm;
                outF[gi] += o[ct];                  // ef residual, slot-ordered
            }
        }
        if (rcv != curRcv) {
            if (curRcv >= 0) {
#pragma unroll
                for (int ct = 0; ct < 8; ++ct)
                    atomicAdd(aggOut + (size_t)curRcv * 128 + ct * 16 + lm, run[ct]);
            }
            curRcv = rcv;
#pragma unroll
            for (int ct = 0; ct < 8; ++ct) run[ct] = o[ct];
        } else {
#pragma unroll
            for (int ct = 0; ct < 8; ++ct) run[ct] += o[ct];
        }
    }
    if (curRcv >= 0) {
#pragma unroll
        for (int ct = 0; ct < 8; ++ct)
            atomicAdd(aggOut + (size_t)curRcv * 128 + ct * 16 + lm, run[ct]);
    }
}

// ---------------------------------------------------------------------------
// r16 generic kernel (encoders / node / decoder) — unchanged
// ---------------------------------------------------------------------------
template<int NW, int MODE, int RESID>
__global__ __launch_bounds__(NW * 64) void gnn_mlp(
    const short* __restrict__ Wt0,
    const short* __restrict__ Wt1, const short* __restrict__ Wt2,
    const float* __restrict__ b0, const float* __restrict__ b1, const float* __restrict__ b2,
    const float* __restrict__ g, const float* __restrict__ be,
    const float* __restrict__ A0f, int K0,
    const short* __restrict__ nfb,
    const float* __restrict__ aggf,
    const int* __restrict__ eList,
    float* __restrict__ outF, short* __restrict__ outB,
    float* __restrict__ aggOut,
    float* __restrict__ decOut,
    int M, int resid)
{
    constexpr int KP0 = (MODE == 2) ? 256 : (MODE == 3) ? 128 : 32;
    constexpr int nC0 = KP0 / 32;
    __shared__ short sH[NW * 32 * SH_STRIDE];
    __shared__ short sW[128 * SW_STRIDE];
    const int tid = threadIdx.x;
    const int lane = tid & 63;
    const int w = tid >> 6;
    const int lm = lane & 15;
    const int lq = lane >> 4;
    const int w32 = w * 32;
    const int m0 = blockIdx.x * (NW * 32);
    constexpr int NT = NW * 64;

    f32x4 acc[2][8];
    zero_acc(acc);

    // -------- layer 0 --------
    if (MODE == 0) {
#pragma unroll
        for (int i = 0; i < 16; ++i) {
            int flat = lane + i * 64;
            int r = flat >> 5, k = flat & 31;
            int row = m0 + w32 + r;
            float v = 0.f;
            if (k < K0 && row < M) {
                int src = eList ? eList[row] : row;    // gather source rows (sorted write)
                v = A0f[(size_t)src * K0 + k];
            }
            sH[(w32 + r) * SH_STRIDE + k] = (short)f2bf(v);
        }
    }
    const int r0m = min(m0 + w32 + lm, M - 1);
    const int r1m = min(m0 + w32 + 16 + lm, M - 1);

    {
        WStage<NT> ws, wsn;
        Frag cur, nx1, nx2;
        wload<NT>(ws, Wt0, KP0, 0, tid);
        load_frag<MODE>(cur, 0, nfb, nullptr, aggf, 0, 0, 0, 0, 0, 0,
                        r0m, r1m, sH, w32, lm, lq);
        if (nC0 > 1)
            load_frag<MODE>(nx1, 1, nfb, nullptr, aggf, 0, 0, 0, 0, 0, 0,
                            r0m, r1m, sH, w32, lm, lq);
#pragma unroll
        for (int c = 0; c < nC0; ++c) {
            if (c + 1 < nC0)
                wload<NT>(wsn, Wt0, KP0, (c + 1) * 32, tid);
            if (c + 2 < nC0)
                load_frag<MODE>(nx2, c + 2, nfb, nullptr, aggf, 0, 0, 0, 0, 0, 0,
                                r0m, r1m, sH, w32, lm, lq);
            bar_lgkm();
            wstore<NT>(ws, sW, tid);
            bar_lgkm();
            bf16x8 u0, u1;
            if (cur.isF) { u0 = pack8(cur.f0, cur.f1); u1 = pack8(cur.f2, cur.f3); }
            else         { u0 = cur.a0;               u1 = cur.a1; }
            mfma_sweep_lds(acc, u0, u1, sW, lm, lq);
            ws = wsn; cur = nx1; nx1 = nx2;
        }
    }
    bar_lgkm();
    park(acc, b0, sH, w32, lm, lq);

    // node mode: zero this block's agg rows (all reads consumed above).
    if (MODE == 2 && aggOut) {
        int totalF4 = NW * 32 * 32;
        for (int i = tid; i < totalF4; i += NT) {
            int r = i >> 5, c4 = i & 31;
            int row = m0 + r;
            if (row < M)
                *(float4*)(aggOut + (size_t)row * 128 + c4 * 4) = make_float4(0.f, 0.f, 0.f, 0.f);
        }
    }

    // -------- layer 1 --------
    zero_acc(acc);
    {
        WStage<NT> ws, wsn;
        wload<NT>(ws, Wt1, 128, 0, tid);
#pragma unroll
        for (int c = 0; c < 4; ++c) {
            if (c + 1 < 4) wload<NT>(wsn, Wt1, 128, (c + 1) * 32, tid);
            bf16x8 a0 = *(const bf16x8*)&sH[(w32 + lm) * SH_STRIDE + c * 32 + lq * 8];
            bf16x8 a1 = *(const bf16x8*)&sH[(w32 + 16 + lm) * SH_STRIDE + c * 32 + lq * 8];
            bar_lgkm();
            wstore<NT>(ws, sW, tid);
            bar_lgkm();
            mfma_sweep_lds(acc, a0, a1, sW, lm, lq);
            ws = wsn;
        }
    }
    bar_lgkm();
    park(acc, b1, sH, w32, lm, lq);

    // -------- decoder tail --------
    if (MODE == 3) {
#pragma unroll
        for (int t = 0; t < 2; ++t) {
            int idx = t * 64 + lane;
            if (idx < 96) {
                int r = idx / 3, o = idx - r * 3;
                int row = m0 + w32 + r;
                if (row < M) {
                    float s = b2[o];
#pragma unroll
                    for (int kk = 0; kk < 16; ++kk) {
                        bf16x8 h8 = *(const bf16x8*)&sH[(w32 + r) * SH_STRIDE + kk * 8];
#pragma unroll
                        for (int j = 0; j < 8; ++j)
                            s += bf2f(h8[j]) * A0f[(kk * 8 + j) * 3 + o];
                    }
                    decOut[(size_t)row * 3 + o] = s;
                }
            }
        }
        return;
    }

    // -------- layer 2 --------
    zero_acc(acc);
    {
        WStage<NT> ws, wsn;
        wload<NT>(ws, Wt2, 128, 0, tid);
#pragma unroll
        for (int c = 0; c < 4; ++c) {
            if (c + 1 < 4) wload<NT>(wsn, Wt2, 128, (c + 1) * 32, tid);
            bf16x8 a0 = *(const bf16x8*)&sH[(w32 + lm) * SH_STRIDE + c * 32 + lq * 8];
            bf16x8 a1 = *(const bf16x8*)&sH[(w32 + 16 + lm) * SH_STRIDE + c * 32 + lq * 8];
            bar_lgkm();
            wstore<NT>(ws, sW, tid);
            bar_lgkm();
            mfma_sweep_lds(acc, a0, a1, sW, lm, lq);
            ws = wsn;
        }
    }

    // -------- epilogue: LN + residual + bf16 shadow --------
    float g_[8], be_[8], b2_[8];
#pragma unroll
    for (int ct = 0; ct < 8; ++ct) {
        g_[ct] = g[ct * 16 + lm]; be_[ct] = be[ct * 16 + lm]; b2_[ct] = b2[ct * 16 + lm];
    }
#pragma unroll
    for (int rt = 0; rt < 2; ++rt) {
#pragma unroll
        for (int reg = 0; reg < 4; ++reg) {
            int row = m0 + w32 + rt * 16 + lq * 4 + reg;
            float v[8];
            float s = 0.f;
#pragma unroll
            for (int ct = 0; ct < 8; ++ct) { v[ct] = acc[rt][ct][reg] + b2_[ct]; s += v[ct]; }
            s += __shfl_xor(s, 1); s += __shfl_xor(s, 2);
            s += __shfl_xor(s, 4); s += __shfl_xor(s, 8);
            float mu = s * (1.f / 128.f);
            float q = 0.f;
#pragma unroll
            for (int ct = 0; ct < 8; ++ct) { v[ct] -= mu; q += v[ct] * v[ct]; }
            q += __shfl_xor(q, 1); q += __shfl_xor(q, 2);
            q += __shfl_xor(q, 4); q += __shfl_xor(q, 8);
            float rs = rsqrtf(q * (1.f / 128.f) + 1e-5f);
            if (row < M) {
#pragma unroll
                for (int ct = 0; ct < 8; ++ct) {
                    float o = v[ct] * rs * g_[ct] + be_[ct];
                    size_t gi = (size_t)row * 128 + ct * 16 + lm;
                    if (resid) {
                        float ns = outF[gi] + o;
                        outF[gi] = ns;
                        if (outB) outB[gi] = (short)f2bf(ns);
                    } else {
                        outF[gi] = o;
                        if (outB) outB[gi] = (short)f2bf(o);
                    }
                }
            }
        }
    }
}

// ---------------------------------------------------------------------------
__global__ void zero_i(int* __restrict__ p, int n)
{
    int i = blockIdx.x * 256 + threadIdx.x;
    if (i < n) p[i] = 0;
}
__global__ void csr_count(const int* __restrict__ recv, int* __restrict__ cnt, int E)
{
    int i = blockIdx.x * 256 + threadIdx.x;
    if (i < E) atomicAdd(&cnt[recv[i]], 1);
}
__global__ __launch_bounds__(256) void csr_scan(const int* __restrict__ cnt,
                                                int* __restrict__ cursor, int N)
{
    __shared__ int ssum[257];
    const int tid = threadIdx.x;
    const int per = (N + 255) / 256;
    const int lo = tid * per, hi = min(lo + per, N);
    int s = 0;
    for (int i = lo; i < hi; ++i) s += cnt[i];
    ssum[tid] = s;
    __syncthreads();
    if (tid == 0) {
        int run = 0;
        for (int i = 0; i < 256; ++i) { int t = ssum[i]; ssum[i] = run; run += t; }
        ssum[256] = run;
    }
    __syncthreads();
    int run = ssum[tid];
    for (int i = lo; i < hi; ++i) { int c = cnt[i]; cursor[i] = run; run += c; }
}
__global__ void csr_fill(const int* __restrict__ recv, int* __restrict__ cursor,
                         int* __restrict__ eList, int E)
{
    int i = blockIdx.x * 256 + threadIdx.x;
    if (i < E) {
        int pos = atomicAdd(&cursor[recv[i]], 1);
        eList[pos] = i;
    }
}

// ---------------------------------------------------------------------------
struct WtPrep { const float* src; int K; int Kpad; int dstOff; };
struct WtPrepAll { WtPrep m[26]; };

__global__ void wt_prep_kernel(WtPrepAll all, short* __restrict__ dst)
{
    const WtPrep p = all.m[blockIdx.y];
    int total = 128 * p.Kpad;
    int idx = blockIdx.x * 256 + threadIdx.x;
    if (idx >= total) return;
    int n = idx / p.Kpad, k = idx - n * p.Kpad;
    float v = (k < p.K) ? p.src[(size_t)k * 128 + n] : 0.f;
    dst[p.dstOff + idx] = (short)f2bf(v);
}

__global__ void zero_kernel(float4* __restrict__ p, long n4)
{
    long i = (long)blockIdx.x * blockDim.x + threadIdx.x;
    if (i < n4) p[i] = make_float4(0.f, 0.f, 0.f, 0.f);
}

// ---------------------------------------------------------------------------
extern "C" void kernel_launch(void* const* d_in, const int* in_sizes, int n_in,
                              void* d_out, int out_size, void* d_ws, size_t ws_size,
                              hipStream_t stream)
{
    const float* node_x   = (const float*)d_in[0];
    const float* edge_x   = (const float*)d_in[1];
    const float* enc_n_W0 = (const float*)d_in[2];
    const float* enc_n_b0 = (const float*)d_in[3];
    const float* enc_n_W1 = (const float*)d_in[4];
    const float* enc_n_b1 = (const float*)d_in[5];
    const float* enc_n_W2 = (const float*)d_in[6];
    const float* enc_n_b2 = (const float*)d_in[7];
    const float* enc_n_g  = (const float*)d_in[8];
    const float* enc_n_be = (const float*)d_in[9];
    const float* enc_e_W0 = (const float*)d_in[10];
    const float* enc_e_b0 = (const float*)d_in[11];
    const float* enc_e_W1 = (const float*)d_in[12];
    const float* enc_e_b1 = (const float*)d_in[13];
    const float* enc_e_W2 = (const float*)d_in[14];
    const float* enc_e_b2 = (const float*)d_in[15];
    const float* enc_e_g  = (const float*)d_in[16];
    const float* enc_e_be = (const float*)d_in[17];
    const float* gnb_e_W0 = (const float*)d_in[18];
    const float* gnb_e_b0 = (const float*)d_in[19];
    const float* gnb_e_W1 = (const float*)d_in[20];
    const float* gnb_e_b1 = (const float*)d_in[21];
    const float* gnb_e_W2 = (const float*)d_in[22];
    const float* gnb_e_b2 = (const float*)d_in[23];
    const float* gnb_e_g  = (const float*)d_in[24];
    const float* gnb_e_be = (const float*)d_in[25];
    const float* gnb_n_W0 = (const float*)d_in[26];
    const float* gnb_n_b0 = (const float*)d_in[27];
    const float* gnb_n_W1 = (const float*)d_in[28];
    const float* gnb_n_b1 = (const float*)d_in[29];
    const float* gnb_n_W2 = (const float*)d_in[30];
    const float* gnb_n_b2 = (const float*)d_in[31];
    const float* gnb_n_g  = (const float*)d_in[32];
    const float* gnb_n_be = (const float*)d_in[33];
    const float* dec_W0   = (const float*)d_in[34];
    const float* dec_b0   = (const float*)d_in[35];
    const float* dec_W1   = (const float*)d_in[36];
    const float* dec_b1   = (const float*)d_in[37];
    const float* dec_W2   = (const float*)d_in[38];
    const float* dec_b2   = (const float*)d_in[39];
    const int*   senders  = (const int*)d_in[40];
    const int*   receivers= (const int*)d_in[41];
    float* out = (float*)d_out;

    const int N = NN, E = EE;
    const int WT_TOTAL = (32 + 128 + 128 + 32 + 128 + 128 + 3 * (384 + 128 + 128 + 256 + 128 + 128)
                          + 128 + 128) * 128;

    // ---- workspace layout: identical to rounds 6..16 (109.26 MB, known-good) ----
    float* nf   = (float*)d_ws;
    float* agg  = nf + (size_t)N * 128;
    float* ef   = agg + (size_t)N * 128;     // stored in SORTED-SLOT order
    short* nfbf = (short*)(ef + (size_t)E * 128);
    short* wt   = nfbf + (size_t)N * 128;
    int*   eList = (int*)(wt + WT_TOTAL);
    size_t need_sorted = (size_t)((char*)(eList + E) - (char*)d_ws);
    int* cnt    = (int*)agg;
    int* cursor = cnt + N;

    const bool useSorted = (ws_size >= need_sorted);
    const int* eL = useSorted ? eList : nullptr;

    WtPrepAll tbl;
    int nMat = 0, off = 0;
    int o_encn[3], o_ence[3], o_ge0[3], o_ge1[3], o_ge2[3], o_gn0[3], o_gn1[3], o_gn2[3], o_dec[2];
    auto add = [&](const float* src, int K, int Kpad) {
        tbl.m[nMat].src = src; tbl.m[nMat].K = K; tbl.m[nMat].Kpad = Kpad;
        tbl.m[nMat].dstOff = off;
        int r = off; off += 128 * Kpad; ++nMat; return r;
    };
    o_encn[0] = add(enc_n_W0, 12, 32);
    o_encn[1] = add(enc_n_W1, 128, 128);
    o_encn[2] = add(enc_n_W2, 128, 128);
    o_ence[0] = add(enc_e_W0, 7, 32);
    o_ence[1] = add(enc_e_W1, 128, 128);
    o_ence[2] = add(enc_e_W2, 128, 128);
    for (int s = 0; s < 3; ++s) {
        o_ge0[s] = add(gnb_e_W0 + (size_t)s * 384 * 128, 384, 384);
        o_ge1[s] = add(gnb_e_W1 + (size_t)s * 128 * 128, 128, 128);
        o_ge2[s] = add(gnb_e_W2 + (size_t)s * 128 * 128, 128, 128);
        o_gn0[s] = add(gnb_n_W0 + (size_t)s * 256 * 128, 256, 256);
        o_gn1[s] = add(gnb_n_W1 + (size_t)s * 128 * 128, 128, 128);
        o_gn2[s] = add(gnb_n_W2 + (size_t)s * 128 * 128, 128, 128);
    }
    o_dec[0] = add(dec_W0, 128, 128);
    o_dec[1] = add(dec_W1, 128, 128);

    wt_prep_kernel<<<dim3(192, 26), 256, 0, stream>>>(tbl, wt);

    if (useSorted) {
        zero_i<<<dim3((N + 255) / 256), 256, 0, stream>>>(cnt, N);
        csr_count<<<dim3((E + 255) / 256), 256, 0, stream>>>(receivers, cnt, E);
        csr_scan<<<dim3(1), 256, 0, stream>>>(cnt, cursor, N);
        csr_fill<<<dim3((E + 255) / 256), 256, 0, stream>>>(receivers, cursor, eList, E);
    }
    // zero agg once (after csr: cnt/cursor overlay agg); steps re-zero in node kernel
    zero_kernel<<<dim3((N * 32 + 255) / 256), 256, 0, stream>>>((float4*)agg, (long)N * 32);

    const dim3 gE(E / 128);                 // edge kernels: 1250 blocks
    const dim3 gN2((N + 63) / 64);          // node kernels: 313 blocks

    // ---- encoders ----
    gnn_mlp<2, 0, 1><<<gN2, 128, 0, stream>>>(wt + o_encn[0], wt + o_encn[1], wt + o_encn[2],
        enc_n_b0, enc_n_b1, enc_n_b2, enc_n_g, enc_n_be,
        node_x, 12, nullptr, nullptr, nullptr,
        nf, nfbf, nullptr, nullptr, N, 0);
    // edge encoder gathers edge_x[eList[slot]] so ef lands in slot order
    gnn_mlp<4, 0, 1><<<gE, 256, 0, stream>>>(wt + o_ence[0], wt + o_ence[1], wt + o_ence[2],
        enc_e_b0, enc_e_b1, enc_e_b2, enc_e_g, enc_e_be,
        edge_x, 7, nullptr, nullptr, eL,
        ef, nullptr, nullptr, nullptr, E, 0);

    // ---- 3 message-passing steps ----
    for (int s = 0; s < 3; ++s) {
        const float* eb0 = gnb_e_b0 + (size_t)s * 128;
        const float* eb1 = gnb_e_b1 + (size_t)s * 128;
        const float* eb2 = gnb_e_b2 + (size_t)s * 128;
        const float* eg  = gnb_e_g  + (size_t)s * 128;
        const float* ebe = gnb_e_be + (size_t)s * 128;
        const float* nb0 = gnb_n_b0 + (size_t)s * 128;
        const float* nb1 = gnb_n_b1 + (size_t)s * 128;
        const float* nb2 = gnb_n_b2 + (size_t)s * 128;
        const float* ng  = gnb_n_g  + (size_t)s * 128;
        const float* nbe = gnb_n_be + (size_t)s * 128;

        if (s < 2) {
            gnn_edge64<1><<<gE, 256, 0, stream>>>(wt + o_ge0[s], wt + o_ge1[s], wt + o_ge2[s],
                eb0, eb1, eb2, eg, ebe,
                nfbf, ef, eL, senders, receivers, ef, agg);
        } else {
            gnn_edge64<0><<<gE, 256, 0, stream>>>(wt + o_ge0[s], wt + o_ge1[s], wt + o_ge2[s],
                eb0, eb1, eb2, eg, ebe,
                nfbf, ef, eL, senders, receivers, ef, agg);
        }
        gnn_mlp<2, 2, 1><<<gN2, 128, 0, stream>>>(wt + o_gn0[s], wt + o_gn1[s], wt + o_gn2[s],
            nb0, nb1, nb2, ng, nbe,
            nullptr, 0, nfbf, agg, nullptr,
            nf, nfbf, agg, nullptr, N, 1);
    }

    // ---- decoder ----
    gnn_mlp<2, 3, 1><<<gN2, 128, 0, stream>>>(wt + o_dec[0], wt + o_dec[1], nullptr,
        dec_b0, dec_b1, dec_b2, nullptr, nullptr,
        dec_W2, 0, nfbf, nullptr, nullptr,
        nullptr, nullptr, nullptr, out, N, 0);
}

// Round 18
// 607.145 us; speedup vs baseline: 1.1589x; 1.0642x over previous
//
#include <hip/hip_runtime.h>
#include <hip/hip_bf16.h>

#define NN 20000
#define EE 160000

typedef __attribute__((ext_vector_type(8))) short bf16x8;
typedef __attribute__((ext_vector_type(4))) float f32x4;

__device__ __forceinline__ unsigned short f2bf(float f) {
    unsigned int u = __float_as_uint(f);
    u += 0x7FFFu + ((u >> 16) & 1);   // RNE
    return (unsigned short)(u >> 16);
}
__device__ __forceinline__ float bf2f(short s) {
    return __uint_as_float(((unsigned int)(unsigned short)s) << 16);
}
__device__ __forceinline__ bf16x8 pack8(float4 a, float4 b) {
    bf16x8 r;
    r[0] = (short)f2bf(a.x); r[1] = (short)f2bf(a.y);
    r[2] = (short)f2bf(a.z); r[3] = (short)f2bf(a.w);
    r[4] = (short)f2bf(b.x); r[5] = (short)f2bf(b.y);
    r[6] = (short)f2bf(b.z); r[7] = (short)f2bf(b.w);
    return r;
}

#define SH_STRIDE 136
#define SW_STRIDE 56
// edge64 kernel strides (LDS = 33792 + 18432 + 1024 = 53248 B -> 3 blocks/CU)
#define SH64 132
#define SW64 72

// barrier that does NOT drain vmcnt (gathers stay in flight)
__device__ __forceinline__ void bar_lgkm() {
    asm volatile("s_waitcnt lgkmcnt(0)\n\ts_barrier" ::: "memory");
}

__device__ __forceinline__ void mfma_sweep_lds(f32x4 (&acc)[2][8], bf16x8 a0, bf16x8 a1,
                                               const short* sWb, int lm, int lq)
{
#pragma unroll
    for (int ct = 0; ct < 8; ++ct) {
        bf16x8 b = *(const bf16x8*)(sWb + (ct * 16 + lm) * SW_STRIDE + lq * 8);
        acc[0][ct] = __builtin_amdgcn_mfma_f32_16x16x32_bf16(a0, b, acc[0][ct], 0, 0, 0);
        acc[1][ct] = __builtin_amdgcn_mfma_f32_16x16x32_bf16(a1, b, acc[1][ct], 0, 0, 0);
    }
}

__device__ __forceinline__ void mfma_sweep64(f32x4 (&acc)[2][8], bf16x8 a0, bf16x8 a1,
                                             const short* sWb, int colOff, int lm)
{
#pragma unroll
    for (int ct = 0; ct < 8; ++ct) {
        bf16x8 b = *(const bf16x8*)(sWb + (ct * 16 + lm) * SW64 + colOff);
        acc[0][ct] = __builtin_amdgcn_mfma_f32_16x16x32_bf16(a0, b, acc[0][ct], 0, 0, 0);
        acc[1][ct] = __builtin_amdgcn_mfma_f32_16x16x32_bf16(a1, b, acc[1][ct], 0, 0, 0);
    }
}

// W-chunk pipeline: load (registers, issued early) / store (ds_write, later).
template<int NT>
struct WStage { bf16x8 v[512 / NT]; };

template<int NT>
__device__ __forceinline__ void wload(WStage<NT>& ws, const short* __restrict__ Wt,
                                      int Kpad, int k0, int tid)
{
#pragma unroll
    for (int j = 0; j < 256 / NT; ++j) {
        int i = tid + j * NT;
        int r = i >> 1, h = i & 1;
        const short* src = Wt + (size_t)r * Kpad + k0 + h * 16;
        ws.v[2 * j]     = *(const bf16x8*)src;
        ws.v[2 * j + 1] = *(const bf16x8*)(src + 8);
    }
}
template<int NT>
__device__ __forceinline__ void wstore(const WStage<NT>& ws, short* __restrict__ sW, int tid)
{
#pragma unroll
    for (int j = 0; j < 256 / NT; ++j) {
        int i = tid + j * NT;
        int r = i >> 1, h = i & 1;
        short* dst = sW + r * SW_STRIDE + h * 16;
        *(bf16x8*)dst       = ws.v[2 * j];
        *(bf16x8*)(dst + 8) = ws.v[2 * j + 1];
    }
}

// 64-k W stage (NT=256): 128 rows x 64 k, 4 bf16x8/thread
struct WStage64 { bf16x8 v[4]; };
__device__ __forceinline__ void wload64(WStage64& ws, const short* __restrict__ Wt,
                                        int Kpad, int k0, int tid)
{
#pragma unroll
    for (int j = 0; j < 4; ++j) {
        int i = tid + j * 256;
        int r = i >> 3, h = i & 7;
        ws.v[j] = *(const bf16x8*)(Wt + (size_t)r * Kpad + k0 + h * 8);
    }
}
__device__ __forceinline__ void wstore64(const WStage64& ws, short* __restrict__ sW, int tid)
{
#pragma unroll
    for (int j = 0; j < 4; ++j) {
        int i = tid + j * 256;
        int r = i >> 3, h = i & 7;
        *(bf16x8*)(sW + r * SW64 + h * 8) = ws.v[j];
    }
}

__device__ __forceinline__ void zero_acc(f32x4 (&acc)[2][8]) {
#pragma unroll
    for (int i = 0; i < 2; ++i)
#pragma unroll
        for (int j = 0; j < 8; ++j) acc[i][j] = (f32x4)(0.f);
}

__device__ __forceinline__ void park(const f32x4 (&acc)[2][8], const float* __restrict__ bias,
                                     short* __restrict__ sH, int w32, int lm, int lq)
{
#pragma unroll
    for (int ct = 0; ct < 8; ++ct) {
        float bb = bias[ct * 16 + lm];
#pragma unroll
        for (int rt = 0; rt < 2; ++rt) {
            int rbase = w32 + rt * 16 + lq * 4;
#pragma unroll
            for (int reg = 0; reg < 4; ++reg) {
                float v = fmaxf(acc[rt][ct][reg] + bb, 0.f);
                sH[(rbase + reg) * SH_STRIDE + ct * 16 + lm] = (short)f2bf(v);
            }
        }
    }
}

__device__ __forceinline__ void park64(const f32x4 (&acc)[2][8], const float* __restrict__ bias,
                                       short* __restrict__ sH, int w32, int lm, int lq)
{
#pragma unroll
    for (int ct = 0; ct < 8; ++ct) {
        float bb = bias[ct * 16 + lm];
#pragma unroll
        for (int rt = 0; rt < 2; ++rt) {
            int rbase = w32 + rt * 16 + lq * 4;
#pragma unroll
            for (int reg = 0; reg < 4; ++reg) {
                float v = fmaxf(acc[rt][ct][reg] + bb, 0.f);
                sH[(rbase + reg) * SH64 + ct * 16 + lm] = (short)f2bf(v);
            }
        }
    }
}

struct Frag {
    bf16x8 a0, a1;
    float4 f0, f1, f2, f3;
    int isF;
};

template<int MODE>
__device__ __forceinline__ void load_frag(Frag& fr, int c,
    const short* __restrict__ nfb, const float* __restrict__ aggf,
    int r0m, int r1m, const short* sH, int w32, int lm, int lq)
{
    int kq = lq * 8;
    fr.isF = 0;
    if (MODE == 0) {
        fr.a0 = *(const bf16x8*)&sH[(w32 + lm) * SH_STRIDE + c * 32 + kq];
        fr.a1 = *(const bf16x8*)&sH[(w32 + 16 + lm) * SH_STRIDE + c * 32 + kq];
    } else if (MODE == 2) {
        int seg = c >> 2, kb = (c & 3) * 32 + kq;
        if (seg == 0) {
            fr.a0 = *(const bf16x8*)(nfb + (size_t)r0m * 128 + kb);
            fr.a1 = *(const bf16x8*)(nfb + (size_t)r1m * 128 + kb);
        } else {
            const float* p0 = aggf + (size_t)r0m * 128 + kb;
            const float* p1 = aggf + (size_t)r1m * 128 + kb;
            fr.f0 = *(const float4*)p0; fr.f1 = *(const float4*)(p0 + 4);
            fr.f2 = *(const float4*)p1; fr.f3 = *(const float4*)(p1 + 4);
            fr.isF = 1;
        }
    } else {
        int kb = c * 32 + kq;
        fr.a0 = *(const bf16x8*)(nfb + (size_t)r0m * 128 + kb);
        fr.a1 = *(const bf16x8*)(nfb + (size_t)r1m * 128 + kb);
    }
}

// 64-k fragment: uniform bf16 (ef master is now bf16-hi) -> 16 VGPRs/frag
struct Frag64 { bf16x8 a[4]; };   // [0]=r0 h0, [1]=r1 h0, [2]=r0 h1, [3]=r1 h1

__device__ __forceinline__ void load_frag64(Frag64& fr, int c,
    const short* __restrict__ nfb, const short* __restrict__ efHi,
    int iS0, int iS1, int iR0, int iR1, size_t eO0, size_t eO1, int lq)
{
    int kb = (c & 1) * 64 + lq * 8;
    int seg = c >> 1;
    const short *base0, *base1;
    if (seg == 0)      { base0 = nfb + (size_t)iS0 * 128; base1 = nfb + (size_t)iS1 * 128; }
    else if (seg == 1) { base0 = nfb + (size_t)iR0 * 128; base1 = nfb + (size_t)iR1 * 128; }
    else               { base0 = efHi + eO0;              base1 = efHi + eO1; }
    fr.a[0] = *(const bf16x8*)(base0 + kb);
    fr.a[1] = *(const bf16x8*)(base1 + kb);
    fr.a[2] = *(const bf16x8*)(base0 + kb + 32);
    fr.a[3] = *(const bf16x8*)(base1 + kb + 32);
}

// ---------------------------------------------------------------------------
// Edge MLP kernel, 64-k chunks, bf16-pair ef master.
// RESID=1: ef(hi,lo) += new_ef (split-float RMW). RESID=0: no ef writeback.
// ---------------------------------------------------------------------------
template<int RESID>
__global__ __launch_bounds__(256) void gnn_edge64(
    const short* __restrict__ Wt0,
    const short* __restrict__ Wt1, const short* __restrict__ Wt2,
    const float* __restrict__ b0, const float* __restrict__ b1, const float* __restrict__ b2,
    const float* __restrict__ g, const float* __restrict__ be,
    const short* __restrict__ nfb,
    short* __restrict__ efHi, short* __restrict__ efLo,
    const int* __restrict__ eList,
    const int* __restrict__ senders, const int* __restrict__ receivers,
    float* __restrict__ aggOut)
{
    __shared__ short sH[128 * SH64];
    __shared__ short sW[128 * SW64];
    __shared__ int sRcv[128], sSnd[128];
    const int tid = threadIdx.x;
    const int lane = tid & 63;
    const int w = tid >> 6;
    const int lm = lane & 15;
    const int lq = lane >> 4;
    const int w32 = w * 32;
    const int m0 = blockIdx.x * 128;

    if (tid < 128) {
        int slot = m0 + tid;                       // grid exact: slot < E
        int e = eList ? eList[slot] : slot;
        sRcv[tid] = receivers[e];
        sSnd[tid] = senders[e];
    }
    bar_lgkm();

    f32x4 acc[2][8];
    zero_acc(acc);

    // rt-interleaved: MFMA row m of tile rt <-> sorted slot w32 + 2*m + rt.
    const int s0 = w32 + 2 * lm, s1 = s0 + 1;
    const int iS0 = sSnd[s0], iS1 = sSnd[s1];
    const int iR0 = sRcv[s0], iR1 = sRcv[s1];
    const size_t eO0 = (size_t)(m0 + s0) * 128;
    const size_t eO1 = (size_t)(m0 + s1) * 128;

    // -------- layer 0: K=384 in 6 chunks of 64 --------
    {
        WStage64 ws, wsn;
        Frag64 cur, nxt;
        wload64(ws, Wt0, 384, 0, tid);
        load_frag64(cur, 0, nfb, efHi, iS0, iS1, iR0, iR1, eO0, eO1, lq);
#pragma unroll
        for (int c = 0; c < 6; ++c) {
            if (c + 1 < 6) {
                wload64(wsn, Wt0, 384, (c + 1) * 64, tid);
                load_frag64(nxt, c + 1, nfb, efHi, iS0, iS1, iR0, iR1, eO0, eO1, lq);
            }
            bar_lgkm();
            wstore64(ws, sW, tid);
            bar_lgkm();
            mfma_sweep64(acc, cur.a[0], cur.a[1], sW, lq * 8, lm);
            mfma_sweep64(acc, cur.a[2], cur.a[3], sW, 32 + lq * 8, lm);
            ws = wsn; cur = nxt;
        }
    }
    bar_lgkm();
    park64(acc, b0, sH, w32, lm, lq);

    // -------- layer 1: 2 chunks of 64 --------
    zero_acc(acc);
    {
        WStage64 ws, wsn;
        wload64(ws, Wt1, 128, 0, tid);
#pragma unroll
        for (int c = 0; c < 2; ++c) {
            if (c == 0) wload64(wsn, Wt1, 128, 64, tid);
            bf16x8 a0h0 = *(const bf16x8*)&sH[(w32 + lm) * SH64 + c * 64 + lq * 8];
            bf16x8 a1h0 = *(const bf16x8*)&sH[(w32 + 16 + lm) * SH64 + c * 64 + lq * 8];
            bf16x8 a0h1 = *(const bf16x8*)&sH[(w32 + lm) * SH64 + c * 64 + 32 + lq * 8];
            bf16x8 a1h1 = *(const bf16x8*)&sH[(w32 + 16 + lm) * SH64 + c * 64 + 32 + lq * 8];
            bar_lgkm();
            wstore64(ws, sW, tid);
            bar_lgkm();
            mfma_sweep64(acc, a0h0, a1h0, sW, lq * 8, lm);
            mfma_sweep64(acc, a0h1, a1h1, sW, 32 + lq * 8, lm);
            ws = wsn;
        }
    }
    bar_lgkm();
    park64(acc, b1, sH, w32, lm, lq);

    // -------- layer 2: 2 chunks of 64 --------
    zero_acc(acc);
    {
        WStage64 ws, wsn;
        wload64(ws, Wt2, 128, 0, tid);
#pragma unroll
        for (int c = 0; c < 2; ++c) {
            if (c == 0) wload64(wsn, Wt2, 128, 64, tid);
            bf16x8 a0h0 = *(const bf16x8*)&sH[(w32 + lm) * SH64 + c * 64 + lq * 8];
            bf16x8 a1h0 = *(const bf16x8*)&sH[(w32 + 16 + lm) * SH64 + c * 64 + lq * 8];
            bf16x8 a0h1 = *(const bf16x8*)&sH[(w32 + lm) * SH64 + c * 64 + 32 + lq * 8];
            bf16x8 a1h1 = *(const bf16x8*)&sH[(w32 + 16 + lm) * SH64 + c * 64 + 32 + lq * 8];
            bar_lgkm();
            wstore64(ws, sW, tid);
            bar_lgkm();
            mfma_sweep64(acc, a0h0, a1h0, sW, lq * 8, lm);
            mfma_sweep64(acc, a0h1, a1h1, sW, 32 + lq * 8, lm);
            ws = wsn;
        }
    }

    // -------- epilogue: LN + (RESID ? split-float ef RMW) + merged-run atomics
    float g_[8], be_[8], b2_[8];
#pragma unroll
    for (int ct = 0; ct < 8; ++ct) {
        g_[ct] = g[ct * 16 + lm]; be_[ct] = be[ct * 16 + lm]; b2_[ct] = b2[ct * 16 + lm];
    }
    float run[8];
    int curRcv = -1;
#pragma unroll
    for (int j = 0; j < 8; ++j) {
        int rt = j & 1, reg = j >> 1;
        int rloc = w32 + lq * 8 + j;
        float v[8];
        float s = 0.f;
#pragma unroll
        for (int ct = 0; ct < 8; ++ct) { v[ct] = acc[rt][ct][reg] + b2_[ct]; s += v[ct]; }
        s += __shfl_xor(s, 1); s += __shfl_xor(s, 2);
        s += __shfl_xor(s, 4); s += __shfl_xor(s, 8);
        float mu = s * (1.f / 128.f);
        float q = 0.f;
#pragma unroll
        for (int ct = 0; ct < 8; ++ct) { v[ct] -= mu; q += v[ct] * v[ct]; }
        q += __shfl_xor(q, 1); q += __shfl_xor(q, 2);
        q += __shfl_xor(q, 4); q += __shfl_xor(q, 8);
        float rs = rsqrtf(q * (1.f / 128.f) + 1e-5f);
        int rcv = sRcv[rloc];
        float o[8];
#pragma unroll
        for (int ct = 0; ct < 8; ++ct) {
            o[ct] = v[ct] * rs * g_[ct] + be_[ct];
            if (RESID) {
                size_t gi = (size_t)(m0 + rloc) * 128 + ct * 16 + lm;
                float x = bf2f(efHi[gi]) + bf2f(efLo[gi]) + o[ct];
                short h = (short)f2bf(x);
                efHi[gi] = h;
                efLo[gi] = (short)f2bf(x - bf2f(h));
            }
        }
        if (rcv != curRcv) {
            if (curRcv >= 0) {
#pragma unroll
                for (int ct = 0; ct < 8; ++ct)
                    atomicAdd(aggOut + (size_t)curRcv * 128 + ct * 16 + lm, run[ct]);
            }
            curRcv = rcv;
#pragma unroll
            for (int ct = 0; ct < 8; ++ct) run[ct] = o[ct];
        } else {
#pragma unroll
            for (int ct = 0; ct < 8; ++ct) run[ct] += o[ct];
        }
    }
    if (curRcv >= 0) {
#pragma unroll
        for (int ct = 0; ct < 8; ++ct)
            atomicAdd(aggOut + (size_t)curRcv * 128 + ct * 16 + lm, run[ct]);
    }
}

// ---------------------------------------------------------------------------
// Generic kernel (encoders / node / decoder). PAIR=1: write bf16 hi/lo pair
// (edge encoder). PAIR=0: fp32 outF (+bf16 shadow outB) as before.
// ---------------------------------------------------------------------------
template<int NW, int MODE, int PAIR>
__global__ __launch_bounds__(NW * 64) void gnn_mlp(
    const short* __restrict__ Wt0,
    const short* __restrict__ Wt1, const short* __restrict__ Wt2,
    const float* __restrict__ b0, const float* __restrict__ b1, const float* __restrict__ b2,
    const float* __restrict__ g, const float* __restrict__ be,
    const float* __restrict__ A0f, int K0,
    const short* __restrict__ nfb,
    const float* __restrict__ aggf,
    const int* __restrict__ eList,
    float* __restrict__ outF, short* __restrict__ outB, short* __restrict__ outB2,
    float* __restrict__ aggOut,
    float* __restrict__ decOut,
    int M, int resid)
{
    constexpr int KP0 = (MODE == 2) ? 256 : (MODE == 3) ? 128 : 32;
    constexpr int nC0 = KP0 / 32;
    __shared__ short sH[NW * 32 * SH_STRIDE];
    __shared__ short sW[128 * SW_STRIDE];
    const int tid = threadIdx.x;
    const int lane = tid & 63;
    const int w = tid >> 6;
    const int lm = lane & 15;
    const int lq = lane >> 4;
    const int w32 = w * 32;
    const int m0 = blockIdx.x * (NW * 32);
    constexpr int NT = NW * 64;

    f32x4 acc[2][8];
    zero_acc(acc);

    // -------- layer 0 --------
    if (MODE == 0) {
#pragma unroll
        for (int i = 0; i < 16; ++i) {
            int flat = lane + i * 64;
            int r = flat >> 5, k = flat & 31;
            int row = m0 + w32 + r;
            float v = 0.f;
            if (k < K0 && row < M) {
                int src = eList ? eList[row] : row;    // gather source rows (sorted write)
                v = A0f[(size_t)src * K0 + k];
            }
            sH[(w32 + r) * SH_STRIDE + k] = (short)f2bf(v);
        }
    }
    const int r0m = min(m0 + w32 + lm, M - 1);
    const int r1m = min(m0 + w32 + 16 + lm, M - 1);

    {
        WStage<NT> ws, wsn;
        Frag cur, nx1, nx2;
        wload<NT>(ws, Wt0, KP0, 0, tid);
        load_frag<MODE>(cur, 0, nfb, aggf, r0m, r1m, sH, w32, lm, lq);
        if (nC0 > 1)
            load_frag<MODE>(nx1, 1, nfb, aggf, r0m, r1m, sH, w32, lm, lq);
#pragma unroll
        for (int c = 0; c < nC0; ++c) {
            if (c + 1 < nC0)
                wload<NT>(wsn, Wt0, KP0, (c + 1) * 32, tid);
            if (c + 2 < nC0)
                load_frag<MODE>(nx2, c + 2, nfb, aggf, r0m, r1m, sH, w32, lm, lq);
            bar_lgkm();
            wstore<NT>(ws, sW, tid);
            bar_lgkm();
            bf16x8 u0, u1;
            if (cur.isF) { u0 = pack8(cur.f0, cur.f1); u1 = pack8(cur.f2, cur.f3); }
            else         { u0 = cur.a0;               u1 = cur.a1; }
            mfma_sweep_lds(acc, u0, u1, sW, lm, lq);
            ws = wsn; cur = nx1; nx1 = nx2;
        }
    }
    bar_lgkm();
    park(acc, b0, sH, w32, lm, lq);

    // node mode: zero this block's agg rows (all reads consumed above).
    if (MODE == 2 && aggOut) {
        int totalF4 = NW * 32 * 32;
        for (int i = tid; i < totalF4; i += NT) {
            int r = i >> 5, c4 = i & 31;
            int row = m0 + r;
            if (row < M)
                *(float4*)(aggOut + (size_t)row * 128 + c4 * 4) = make_float4(0.f, 0.f, 0.f, 0.f);
        }
    }

    // -------- layer 1 --------
    zero_acc(acc);
    {
        WStage<NT> ws, wsn;
        wload<NT>(ws, Wt1, 128, 0, tid);
#pragma unroll
        for (int c = 0; c < 4; ++c) {
            if (c + 1 < 4) wload<NT>(wsn, Wt1, 128, (c + 1) * 32, tid);
            bf16x8 a0 = *(const bf16x8*)&sH[(w32 + lm) * SH_STRIDE + c * 32 + lq * 8];
            bf16x8 a1 = *(const bf16x8*)&sH[(w32 + 16 + lm) * SH_STRIDE + c * 32 + lq * 8];
            bar_lgkm();
            wstore<NT>(ws, sW, tid);
            bar_lgkm();
            mfma_sweep_lds(acc, a0, a1, sW, lm, lq);
            ws = wsn;
        }
    }
    bar_lgkm();
    park(acc, b1, sH, w32, lm, lq);

    // -------- decoder tail --------
    if (MODE == 3) {
#pragma unroll
        for (int t = 0; t < 2; ++t) {
            int idx = t * 64 + lane;
            if (idx < 96) {
                int r = idx / 3, o = idx - r * 3;
                int row = m0 + w32 + r;
                if (row < M) {
                    float s = b2[o];
#pragma unroll
                    for (int kk = 0; kk < 16; ++kk) {
                        bf16x8 h8 = *(const bf16x8*)&sH[(w32 + r) * SH_STRIDE + kk * 8];
#pragma unroll
                        for (int j = 0; j < 8; ++j)
                            s += bf2f(h8[j]) * A0f[(kk * 8 + j) * 3 + o];
                    }
                    decOut[(size_t)row * 3 + o] = s;
                }
            }
        }
        return;
    }

    // -------- layer 2 --------
    zero_acc(acc);
    {
        WStage<NT> ws, wsn;
        wload<NT>(ws, Wt2, 128, 0, tid);
#pragma unroll
        for (int c = 0; c < 4; ++c) {
            if (c + 1 < 4) wload<NT>(wsn, Wt2, 128, (c + 1) * 32, tid);
            bf16x8 a0 = *(const bf16x8*)&sH[(w32 + lm) * SH_STRIDE + c * 32 + lq * 8];
            bf16x8 a1 = *(const bf16x8*)&sH[(w32 + 16 + lm) * SH_STRIDE + c * 32 + lq * 8];
            bar_lgkm();
            wstore<NT>(ws, sW, tid);
            bar_lgkm();
            mfma_sweep_lds(acc, a0, a1, sW, lm, lq);
            ws = wsn;
        }
    }

    // -------- epilogue: LN + (PAIR ? hi/lo write : fp32 + shadow) --------
    float g_[8], be_[8], b2_[8];
#pragma unroll
    for (int ct = 0; ct < 8; ++ct) {
        g_[ct] = g[ct * 16 + lm]; be_[ct] = be[ct * 16 + lm]; b2_[ct] = b2[ct * 16 + lm];
    }
#pragma unroll
    for (int rt = 0; rt < 2; ++rt) {
#pragma unroll
        for (int reg = 0; reg < 4; ++reg) {
            int row = m0 + w32 + rt * 16 + lq * 4 + reg;
            float v[8];
            float s = 0.f;
#pragma unroll
            for (int ct = 0; ct < 8; ++ct) { v[ct] = acc[rt][ct][reg] + b2_[ct]; s += v[ct]; }
            s += __shfl_xor(s, 1); s += __shfl_xor(s, 2);
            s += __shfl_xor(s, 4); s += __shfl_xor(s, 8);
            float mu = s * (1.f / 128.f);
            float q = 0.f;
#pragma unroll
            for (int ct = 0; ct < 8; ++ct) { v[ct] -= mu; q += v[ct] * v[ct]; }
            q += __shfl_xor(q, 1); q += __shfl_xor(q, 2);
            q += __shfl_xor(q, 4); q += __shfl_xor(q, 8);
            float rs = rsqrtf(q * (1.f / 128.f) + 1e-5f);
            if (row < M) {
#pragma unroll
                for (int ct = 0; ct < 8; ++ct) {
                    float o = v[ct] * rs * g_[ct] + be_[ct];
                    size_t gi = (size_t)row * 128 + ct * 16 + lm;
                    if (PAIR) {
                        short h = (short)f2bf(o);
                        outB[gi]  = h;
                        outB2[gi] = (short)f2bf(o - bf2f(h));
                    } else {
                        if (resid) {
                            float ns = outF[gi] + o;
                            outF[gi] = ns;
                            if (outB) outB[gi] = (short)f2bf(ns);
                        } else {
                            outF[gi] = o;
                            if (outB) outB[gi] = (short)f2bf(o);
                        }
                    }
                }
            }
        }
    }
}

// ---------------------------------------------------------------------------
__global__ void zero_i(int* __restrict__ p, int n)
{
    int i = blockIdx.x * 256 + threadIdx.x;
    if (i < n) p[i] = 0;
}
__global__ void csr_count(const int* __restrict__ recv, int* __restrict__ cnt, int E)
{
    int i = blockIdx.x * 256 + threadIdx.x;
    if (i < E) atomicAdd(&cnt[recv[i]], 1);
}
__global__ __launch_bounds__(256) void csr_scan(const int* __restrict__ cnt,
                                                int* __restrict__ cursor, int N)
{
    __shared__ int ssum[257];
    const int tid = threadIdx.x;
    const int per = (N + 255) / 256;
    const int lo = tid * per, hi = min(lo + per, N);
    int s = 0;
    for (int i = lo; i < hi; ++i) s += cnt[i];
    ssum[tid] = s;
    __syncthreads();
    if (tid == 0) {
        int run = 0;
        for (int i = 0; i < 256; ++i) { int t = ssum[i]; ssum[i] = run; run += t; }
        ssum[256] = run;
    }
    __syncthreads();
    int run = ssum[tid];
    for (int i = lo; i < hi; ++i) { int c = cnt[i]; cursor[i] = run; run += c; }
}
__global__ void csr_fill(const int* __restrict__ recv, int* __restrict__ cursor,
                         int* __restrict__ eList, int E)
{
    int i = blockIdx.x * 256 + threadIdx.x;
    if (i < E) {
        int pos = atomicAdd(&cursor[recv[i]], 1);
        eList[pos] = i;
    }
}

// ---------------------------------------------------------------------------
struct WtPrep { const float* src; int K; int Kpad; int dstOff; };
struct WtPrepAll { WtPrep m[26]; };

__global__ void wt_prep_kernel(WtPrepAll all, short* __restrict__ dst)
{
    const WtPrep p = all.m[blockIdx.y];
    int total = 128 * p.Kpad;
    int idx = blockIdx.x * 256 + threadIdx.x;
    if (idx >= total) return;
    int n = idx / p.Kpad, k = idx - n * p.Kpad;
    float v = (k < p.K) ? p.src[(size_t)k * 128 + n] : 0.f;
    dst[p.dstOff + idx] = (short)f2bf(v);
}

__global__ void zero_kernel(float4* __restrict__ p, long n4)
{
    long i = (long)blockIdx.x * blockDim.x + threadIdx.x;
    if (i < n4) p[i] = make_float4(0.f, 0.f, 0.f, 0.f);
}

// ---------------------------------------------------------------------------
extern "C" void kernel_launch(void* const* d_in, const int* in_sizes, int n_in,
                              void* d_out, int out_size, void* d_ws, size_t ws_size,
                              hipStream_t stream)
{
    const float* node_x   = (const float*)d_in[0];
    const float* edge_x   = (const float*)d_in[1];
    const float* enc_n_W0 = (const float*)d_in[2];
    const float* enc_n_b0 = (const float*)d_in[3];
    const float* enc_n_W1 = (const float*)d_in[4];
    const float* enc_n_b1 = (const float*)d_in[5];
    const float* enc_n_W2 = (const float*)d_in[6];
    const float* enc_n_b2 = (const float*)d_in[7];
    const float* enc_n_g  = (const float*)d_in[8];
    const float* enc_n_be = (const float*)d_in[9];
    const float* enc_e_W0 = (const float*)d_in[10];
    const float* enc_e_b0 = (const float*)d_in[11];
    const float* enc_e_W1 = (const float*)d_in[12];
    const float* enc_e_b1 = (const float*)d_in[13];
    const float* enc_e_W2 = (const float*)d_in[14];
    const float* enc_e_b2 = (const float*)d_in[15];
    const float* enc_e_g  = (const float*)d_in[16];
    const float* enc_e_be = (const float*)d_in[17];
    const float* gnb_e_W0 = (const float*)d_in[18];
    const float* gnb_e_b0 = (const float*)d_in[19];
    const float* gnb_e_W1 = (const float*)d_in[20];
    const float* gnb_e_b1 = (const float*)d_in[21];
    const float* gnb_e_W2 = (const float*)d_in[22];
    const float* gnb_e_b2 = (const float*)d_in[23];
    const float* gnb_e_g  = (const float*)d_in[24];
    const float* gnb_e_be = (const float*)d_in[25];
    const float* gnb_n_W0 = (const float*)d_in[26];
    const float* gnb_n_b0 = (const float*)d_in[27];
    const float* gnb_n_W1 = (const float*)d_in[28];
    const float* gnb_n_b1 = (const float*)d_in[29];
    const float* gnb_n_W2 = (const float*)d_in[30];
    const float* gnb_n_b2 = (const float*)d_in[31];
    const float* gnb_n_g  = (const float*)d_in[32];
    const float* gnb_n_be = (const float*)d_in[33];
    const float* dec_W0   = (const float*)d_in[34];
    const float* dec_b0   = (const float*)d_in[35];
    const float* dec_W1   = (const float*)d_in[36];
    const float* dec_b1   = (const float*)d_in[37];
    const float* dec_W2   = (const float*)d_in[38];
    const float* dec_b2   = (const float*)d_in[39];
    const int*   senders  = (const int*)d_in[40];
    const int*   receivers= (const int*)d_in[41];
    float* out = (float*)d_out;

    const int N = NN, E = EE;
    const int WT_TOTAL = (32 + 128 + 128 + 32 + 128 + 128 + 3 * (384 + 128 + 128 + 256 + 128 + 128)
                          + 128 + 128) * 128;

    // ---- workspace layout: SAME total bytes as rounds 6..17 (109.26 MB) ----
    // ef fp32 (82 MB) replaced by bf16 hi/lo pair (41 + 41 MB), slot-ordered.
    float* nf   = (float*)d_ws;                      // N*128 f32
    float* agg  = nf + (size_t)N * 128;              // N*128 f32
    short* efHi = (short*)(agg + (size_t)N * 128);   // E*128 bf16 (slot order)
    short* efLo = efHi + (size_t)E * 128;            // E*128 bf16
    short* nfbf = efLo + (size_t)E * 128;            // N*128 bf16
    short* wt   = nfbf + (size_t)N * 128;            // WT_TOTAL bf16
    int*   eList = (int*)(wt + WT_TOTAL);            // E ints
    size_t need_sorted = (size_t)((char*)(eList + E) - (char*)d_ws);
    int* cnt    = (int*)agg;                          // transient overlay on agg
    int* cursor = cnt + N;

    const bool useSorted = (ws_size >= need_sorted);
    const int* eL = useSorted ? eList : nullptr;

    WtPrepAll tbl;
    int nMat = 0, off = 0;
    int o_encn[3], o_ence[3], o_ge0[3], o_ge1[3], o_ge2[3], o_gn0[3], o_gn1[3], o_gn2[3], o_dec[2];
    auto add = [&](const float* src, int K, int Kpad) {
        tbl.m[nMat].src = src; tbl.m[nMat].K = K; tbl.m[nMat].Kpad = Kpad;
        tbl.m[nMat].dstOff = off;
        int r = off; off += 128 * Kpad; ++nMat; return r;
    };
    o_encn[0] = add(enc_n_W0, 12, 32);
    o_encn[1] = add(enc_n_W1, 128, 128);
    o_encn[2] = add(enc_n_W2, 128, 128);
    o_ence[0] = add(enc_e_W0, 7, 32);
    o_ence[1] = add(enc_e_W1, 128, 128);
    o_ence[2] = add(enc_e_W2, 128, 128);
    for (int s = 0; s < 3; ++s) {
        o_ge0[s] = add(gnb_e_W0 + (size_t)s * 384 * 128, 384, 384);
        o_ge1[s] = add(gnb_e_W1 + (size_t)s * 128 * 128, 128, 128);
        o_ge2[s] = add(gnb_e_W2 + (size_t)s * 128 * 128, 128, 128);
        o_gn0[s] = add(gnb_n_W0 + (size_t)s * 256 * 128, 256, 256);
        o_gn1[s] = add(gnb_n_W1 + (size_t)s * 128 * 128, 128, 128);
        o_gn2[s] = add(gnb_n_W2 + (size_t)s * 128 * 128, 128, 128);
    }
    o_dec[0] = add(dec_W0, 128, 128);
    o_dec[1] = add(dec_W1, 128, 128);

    wt_prep_kernel<<<dim3(192, 26), 256, 0, stream>>>(tbl, wt);

    if (useSorted) {
        zero_i<<<dim3((N + 255) / 256), 256, 0, stream>>>(cnt, N);
        csr_count<<<dim3((E + 255) / 256), 256, 0, stream>>>(receivers, cnt, E);
        csr_scan<<<dim3(1), 256, 0, stream>>>(cnt, cursor, N);
        csr_fill<<<dim3((E + 255) / 256), 256, 0, stream>>>(receivers, cursor, eList, E);
    }
    // zero agg once (after csr: cnt/cursor overlay agg); steps re-zero in node kernel
    zero_kernel<<<dim3((N * 32 + 255) / 256), 256, 0, stream>>>((float4*)agg, (long)N * 32);

    const dim3 gE(E / 128);                 // edge kernels: 1250 blocks
    const dim3 gN2((N + 63) / 64);          // node kernels: 313 blocks

    // ---- encoders ----
    gnn_mlp<2, 0, 0><<<gN2, 128, 0, stream>>>(wt + o_encn[0], wt + o_encn[1], wt + o_encn[2],
        enc_n_b0, enc_n_b1, enc_n_b2, enc_n_g, enc_n_be,
        node_x, 12, nullptr, nullptr, nullptr,
        nf, nfbf, nullptr, nullptr, nullptr, N, 0);
    // edge encoder gathers edge_x[eList[slot]]; writes bf16 hi/lo pair slot-ordered
    gnn_mlp<4, 0, 1><<<gE, 256, 0, stream>>>(wt + o_ence[0], wt + o_ence[1], wt + o_ence[2],
        enc_e_b0, enc_e_b1, enc_e_b2, enc_e_g, enc_e_be,
        edge_x, 7, nullptr, nullptr, eL,
        nullptr, efHi, efLo, nullptr, nullptr, E, 0);

    // ---- 3 message-passing steps (last edge step: ef writeback deleted) ----
    for (int s = 0; s < 3; ++s) {
        const float* eb0 = gnb_e_b0 + (size_t)s * 128;
        const float* eb1 = gnb_e_b1 + (size_t)s * 128;
        const float* eb2 = gnb_e_b2 + (size_t)s * 128;
        const float* eg  = gnb_e_g  + (size_t)s * 128;
        const float* ebe = gnb_e_be + (size_t)s * 128;
        const float* nb0 = gnb_n_b0 + (size_t)s * 128;
        const float* nb1 = gnb_n_b1 + (size_t)s * 128;
        const float* nb2 = gnb_n_b2 + (size_t)s * 128;
        const float* ng  = gnb_n_g  + (size_t)s * 128;
        const float* nbe = gnb_n_be + (size_t)s * 128;

        if (s < 2) {
            gnn_edge64<1><<<gE, 256, 0, stream>>>(wt + o_ge0[s], wt + o_ge1[s], wt + o_ge2[s],
                eb0, eb1, eb2, eg, ebe,
                nfbf, efHi, efLo, eL, senders, receivers, agg);
        } else {
            gnn_edge64<0><<<gE, 256, 0, stream>>>(wt + o_ge0[s], wt + o_ge1[s], wt + o_ge2[s],
                eb0, eb1, eb2, eg, ebe,
                nfbf, efHi, efLo, eL, senders, receivers, agg);
        }
        gnn_mlp<2, 2, 0><<<gN2, 128, 0, stream>>>(wt + o_gn0[s], wt + o_gn1[s], wt + o_gn2[s],
            nb0, nb1, nb2, ng, nbe,
            nullptr, 0, nfbf, agg, nullptr,
            nf, nfbf, nullptr, agg, nullptr, N, 1);
    }

    // ---- decoder ----
    gnn_mlp<2, 3, 0><<<gN2, 128, 0, stream>>>(wt + o_dec[0], wt + o_dec[1], nullptr,
        dec_b0, dec_b1, dec_b2, nullptr, nullptr,
        dec_W2, 0, nfbf, nullptr, nullptr,
        nullptr, nullptr, nullptr, nullptr, out, N, 0);
}